// Round 17
// baseline (153.140 us; speedup 1.0000x reference)
//
#include <hip/hip_runtime.h>
#include <stdint.h>

// Pipeline: cvt x,z -> bf16; pack weights; fused QKV GEMM (NEW: 256x256 tile, 8 waves,
// BK=64, 8-phase-style interleaved schedule, 128KB LDS dbuf); flash attention
// (r14/r16-validated staged KVBLK=128, swapped QK^T, XCD-local grid); output GEMM
// (r12-validated 256x128 ring) -> f32.
// v_cvt_pk_bf16_f32 inline asm BANNED (NaN culprit). Direct-from-global K/V BANNED (r15).
// B=8 TX=TZ=1024 DX=DZ=1024 DATT=DMID=64 H=16 DOUT=1024.

typedef float    f32x4  __attribute__((ext_vector_type(4)));
typedef __bf16   bf16x8 __attribute__((ext_vector_type(8)));
typedef unsigned short u16x4 __attribute__((ext_vector_type(4)));
typedef unsigned short u16x8 __attribute__((ext_vector_type(8)));

#define MASKNEG (-3.0e38f)
#define QSCALE_F (0.125f * 1.4426950408889634f)

__device__ __forceinline__ unsigned short f2bf(float f) {
  unsigned int u = __float_as_uint(f);
  u += 0x7fffu + ((u >> 16) & 1u);   // RNE
  return (unsigned short)(u >> 16);
}

__device__ __forceinline__ void gload16(const void* g, void* s) {
  const __attribute__((address_space(1))) unsigned int* gp =
      (const __attribute__((address_space(1))) unsigned int*)(uintptr_t)g;
  __attribute__((address_space(3))) unsigned int* lp =
      (__attribute__((address_space(3))) unsigned int*)(unsigned int)(uintptr_t)s;
  __builtin_amdgcn_global_load_lds(gp, lp, 16, 0, 0);
}

__device__ __forceinline__ f32x4 mfma16(bf16x8 a, bf16x8 b, f32x4 c) {
  return __builtin_amdgcn_mfma_f32_16x16x32_bf16(a, b, c, 0, 0, 0);
}

// ---------------- prep kernels (r12 verbatim) ----------------

__global__ __launch_bounds__(256) void k_cvt2(const float* __restrict__ x,
                                              const float* __restrict__ z,
                                              unsigned short* __restrict__ out) {
  int i = blockIdx.x * 256 + threadIdx.x;
  const int stride = gridDim.x * 256;
  for (; i < 2097152; i += stride) {
    const float* in = (i < 1048576) ? (x + (size_t)i * 8) : (z + (size_t)(i - 1048576) * 8);
    const f32x4* p = (const f32x4*)in;
    f32x4 a = p[0], b = p[1];
    u16x8 o;
    o[0] = f2bf(a[0]); o[1] = f2bf(a[1]); o[2] = f2bf(a[2]); o[3] = f2bf(a[3]);
    o[4] = f2bf(b[0]); o[5] = f2bf(b[1]); o[6] = f2bf(b[2]); o[7] = f2bf(b[3]);
    *(u16x8*)(out + (size_t)i * 8) = o;
  }
}

__global__ __launch_bounds__(256) void k_pack(const float* __restrict__ Wq,
                                              const float* __restrict__ Wk,
                                              const float* __restrict__ Wv,
                                              const float* __restrict__ Wp,
                                              unsigned short* __restrict__ Oq,
                                              unsigned short* __restrict__ Ok,
                                              unsigned short* __restrict__ Ov,
                                              unsigned short* __restrict__ Op) {
  __shared__ float tile[64][65];
  const int t = threadIdx.x;
  const int zid = blockIdx.z;
  if (zid < 3) {
    const float* W = zid == 0 ? Wq : (zid == 1 ? Wk : Wv);
    unsigned short* O = zid == 0 ? Oq : (zid == 1 ? Ok : Ov);
    const int h = blockIdx.x, d0 = blockIdx.y * 64;
    const int ee = t & 63, r0 = t >> 6;
#pragma unroll
    for (int dd = r0; dd < 64; dd += 4)
      tile[dd][ee] = W[(h * 1024 + d0 + dd) * 64 + ee];
    __syncthreads();
    const int d = t & 63, e0 = t >> 6;
#pragma unroll
    for (int e = e0; e < 64; e += 4)
      O[(h * 64 + e) * 1024 + d0 + d] = f2bf(tile[d][e]);
  } else {
    const int k0 = blockIdx.x * 64, n0 = blockIdx.y * 64;
    const int nn = t & 63, r0 = t >> 6;
#pragma unroll
    for (int kk = r0; kk < 64; kk += 4)
      tile[kk][nn] = Wp[(k0 + kk) * 1024 + n0 + nn];
    __syncthreads();
    const int kk = t & 63, e0 = t >> 6;
#pragma unroll
    for (int n2 = e0; n2 < 64; n2 += 4)
      Op[(n0 + n2) * 1024 + k0 + kk] = f2bf(tile[kk][n2]);
  }
}

// ---------------- fused QKV GEMM: 256x256 tile, 8 waves, BK=64, phased schedule ----------------
// LDS: A [2 db][2 mhalf][128 rows][64 k] bf16 = 64 KB; B same for cols = 64 KB. 128 KB.
// Rows are 128 B; swizzle: 16B granule g stored at g ^ (row&7) (attn-validated pattern).
// Wave (wr2, wc2): output rows wr2*128+m*16 (m 0..7), cols wc2*64+n*16 (n 0..3). acc[8][4].
// Per K-tile: 4 phases in gray order (kf,mh) = (0,0),(0,1),(1,1),(1,0): phase = 4 A-frag
// ds_reads (+4 B-frag reads on kf change), 16 MFMA (setprio), s_barrier. Stages of tile
// t+1 go to dbuf^1 in phases 0 (A halves) and 1 (B halves); boundary waits vmcnt(0)
// with >=2 phases of latency cover.
__global__ __launch_bounds__(512, 1) void k_gemm_qkv8(const unsigned short* __restrict__ Xb,
                                                      const unsigned short* __restrict__ Zb,
                                                      const unsigned short* __restrict__ Wqkv,
                                                      const float* __restrict__ bq,
                                                      const float* __restrict__ bk,
                                                      const float* __restrict__ bv,
                                                      unsigned short* __restrict__ Qp,
                                                      unsigned short* __restrict__ Kp,
                                                      unsigned short* __restrict__ Vtp) {
  __shared__ unsigned short As[32768];  // 64 KB
  __shared__ unsigned short Bs[32768];  // 64 KB

  const int tid = threadIdx.x;
  const int l = tid & 63, w = tid >> 6;     // 8 waves
  const int lrow = l & 15, lk = l >> 4;
  const int wr2 = w >> 2, wc2 = w & 3;      // M-half (0..1), N-quarter (0..3)

  const int brow = blockIdx.x * 256;
  const int cg = blockIdx.y;
  const int seg = cg >> 2;                  // 0=Q 1=K 2=V
  const int bcol = (cg & 3) * 256;
  const unsigned short* A = (seg == 0) ? Xb : Zb;
  const unsigned short* Bt = Wqkv + (size_t)seg * 1048576;
  const float* bias = (seg == 0) ? bq : (seg == 1 ? bk : bv);
  const int mode = (seg == 2) ? 2 : 0;
  const float oscale = (seg == 0) ? QSCALE_F : 1.0f;

  // staging: thread covers row srow (+64 for 2nd gload), granule tid&7; pre-swizzled src
  const int srow = tid >> 3;                 // 0..63
  const int presw = ((tid & 7) ^ (srow & 7)) * 8;
  const unsigned short* agp = A + (size_t)(brow + srow) * 1024 + presw;
  const unsigned short* bgp = Bt + (size_t)(bcol + srow) * 1024 + presw;

  // frag read constants
  const int axor = lrow & 7;
  const int albase = wr2 * 16384 + lrow * 128;                    // byte off within A db
  const int blbase = (wc2 >> 1) * 16384 + ((wc2 & 1) * 64 + lrow) * 128;  // within B db

  f32x4 acc[8][4];
#pragma unroll
  for (int n = 0; n < 4; n++) {
    float bv = bias[bcol + wc2 * 64 + n * 16 + lrow];
#pragma unroll
    for (int m = 0; m < 8; m++) acc[m][n] = (f32x4){bv, bv, bv, bv};
  }

  // stage one half (128 rows x 64 k) of matrix into (db, half): 2 gloads (8KB each)
#define STG_A(half, ktn, dbn)                                                      \
  {                                                                                \
    char* d = (char*)As + (dbn) * 32768 + (half) * 16384 + w * 1024;               \
    gload16(agp + (size_t)((half) * 128) * 1024 + (ktn) * 64, d);                  \
    gload16(agp + (size_t)((half) * 128 + 64) * 1024 + (ktn) * 64, d + 8192);      \
  }
#define STG_B(half, ktn, dbn)                                                      \
  {                                                                                \
    char* d = (char*)Bs + (dbn) * 32768 + (half) * 16384 + w * 1024;               \
    gload16(bgp + (size_t)((half) * 128) * 1024 + (ktn) * 64, d);                  \
    gload16(bgp + (size_t)((half) * 128 + 64) * 1024 + (ktn) * 64, d + 8192);      \
  }

  // prologue: tile 0 -> db0
  STG_A(0, 0, 0) STG_A(1, 0, 0) STG_B(0, 0, 0) STG_B(1, 0, 0)
  asm volatile("s_waitcnt vmcnt(0)" ::: "memory");
  __builtin_amdgcn_s_barrier();
  __builtin_amdgcn_sched_barrier(0);

#pragma unroll 1
  for (int kt = 0; kt < 16; kt++) {
    const int db = kt & 1;
    const char* AB = (const char*)As + db * 32768;
    const char* BB = (const char*)Bs + db * 32768;
    bf16x8 afr[4], bfr[4];

    // ---- phase 0: kf=0, mh=0 ----
#pragma unroll
    for (int n = 0; n < 4; n++)
      bfr[n] = *(const bf16x8*)(BB + blbase + n * 2048 + ((lk ^ axor) << 4));
#pragma unroll
    for (int m = 0; m < 4; m++)
      afr[m] = *(const bf16x8*)(AB + albase + m * 2048 + ((lk ^ axor) << 4));
    if (kt < 15) { STG_A(0, kt + 1, db ^ 1) STG_A(1, kt + 1, db ^ 1) }
    __builtin_amdgcn_s_setprio(1);
#pragma unroll
    for (int m = 0; m < 4; m++)
#pragma unroll
      for (int n = 0; n < 4; n++)
        acc[m][n] = mfma16(afr[m], bfr[n], acc[m][n]);
    __builtin_amdgcn_s_setprio(0);
    __builtin_amdgcn_s_barrier();
    __builtin_amdgcn_sched_barrier(0);

    // ---- phase 1: kf=0, mh=1 (B held) ----
#pragma unroll
    for (int m = 0; m < 4; m++)
      afr[m] = *(const bf16x8*)(AB + albase + 8192 + m * 2048 + ((lk ^ axor) << 4));
    if (kt < 15) { STG_B(0, kt + 1, db ^ 1) STG_B(1, kt + 1, db ^ 1) }
    __builtin_amdgcn_s_setprio(1);
#pragma unroll
    for (int m = 0; m < 4; m++)
#pragma unroll
      for (int n = 0; n < 4; n++)
        acc[4 + m][n] = mfma16(afr[m], bfr[n], acc[4 + m][n]);
    __builtin_amdgcn_s_setprio(0);
    __builtin_amdgcn_s_barrier();
    __builtin_amdgcn_sched_barrier(0);

    // ---- phase 2: kf=1, mh=1 ----
#pragma unroll
    for (int n = 0; n < 4; n++)
      bfr[n] = *(const bf16x8*)(BB + blbase + n * 2048 + (((4 + lk) ^ axor) << 4));
#pragma unroll
    for (int m = 0; m < 4; m++)
      afr[m] = *(const bf16x8*)(AB + albase + 8192 + m * 2048 + (((4 + lk) ^ axor) << 4));
    __builtin_amdgcn_s_setprio(1);
#pragma unroll
    for (int m = 0; m < 4; m++)
#pragma unroll
      for (int n = 0; n < 4; n++)
        acc[4 + m][n] = mfma16(afr[m], bfr[n], acc[4 + m][n]);
    __builtin_amdgcn_s_setprio(0);
    __builtin_amdgcn_s_barrier();
    __builtin_amdgcn_sched_barrier(0);

    // ---- phase 3: kf=1, mh=0 (B held) ----
#pragma unroll
    for (int m = 0; m < 4; m++)
      afr[m] = *(const bf16x8*)(AB + albase + m * 2048 + (((4 + lk) ^ axor) << 4));
    __builtin_amdgcn_s_setprio(1);
#pragma unroll
    for (int m = 0; m < 4; m++)
#pragma unroll
      for (int n = 0; n < 4; n++)
        acc[m][n] = mfma16(afr[m], bfr[n], acc[m][n]);
    __builtin_amdgcn_s_setprio(0);

    // ---- tile boundary: tile kt+1 fully landed; youngest load ~2 phases old ----
    if (kt < 15) {
      asm volatile("s_waitcnt vmcnt(0)" ::: "memory");
    }
    __builtin_amdgcn_s_barrier();
    __builtin_amdgcn_sched_barrier(0);
  }
#undef STG_A
#undef STG_B

  // epilogue (r12 formulas; r = brow + wr2*128 + m*16 + 4*lk, c = bcol + wc2*64 + n*16 + lrow)
  if (mode == 0) {
    unsigned short* C = (seg == 0) ? Qp : Kp;
#pragma unroll
    for (int m = 0; m < 8; m++) {
      int r = brow + wr2 * 128 + m * 16 + 4 * lk;
#pragma unroll
      for (int n = 0; n < 4; n++) {
        int c = bcol + wc2 * 64 + n * 16 + lrow;
        unsigned short* p = C + ((r >> 10) * 16 + (c >> 6)) * 65536 + (r & 1023) * 64 + (c & 63);
#pragma unroll
        for (int j = 0; j < 4; j++) p[j * 64] = f2bf(acc[m][n][j] * oscale);
      }
    }
  } else {
    unsigned short* C = Vtp;
#pragma unroll
    for (int m = 0; m < 8; m++) {
      int r = brow + wr2 * 128 + m * 16 + 4 * lk;
#pragma unroll
      for (int n = 0; n < 4; n++) {
        int c = bcol + wc2 * 64 + n * 16 + lrow;
        u16x4 o;
#pragma unroll
        for (int j = 0; j < 4; j++) o[j] = f2bf(acc[m][n][j]);
        *(u16x4*)(C + ((r >> 10) * 16 + (c >> 6)) * 65536 + (c & 63) * 1024 + (r & 1023)) = o;
      }
    }
  }
}

// ---------------- final GEMM body (r12 verbatim, 256 threads) ----------------
__device__ __forceinline__ void gemm_body(const unsigned short* __restrict__ A,
                                          const unsigned short* __restrict__ Bt,
                                          const float* __restrict__ bias,
                                          void* __restrict__ outp,
                                          int mode, float oscale,
                                          int brow, int bcol,
                                          unsigned short* As, unsigned short* Bs) {
  const int tid = threadIdx.x;
  const int l = tid & 63, w = tid >> 6;
  const int lrow = l & 15, lk = l >> 4;
  const int wr = (w >> 1) * 128, wc = (w & 1) * 64;

  const int arow = tid >> 2;
  const int asrc = ((tid & 3) ^ ((arow >> 1) & 3)) * 8;
  const unsigned short* ag0 = A + (size_t)(brow + arow) * 1024 + asrc;
  const unsigned short* bg0 = Bt + (size_t)(bcol + arow) * 1024 + asrc;

  int aoff[8], boff[4];
#pragma unroll
  for (int m = 0; m < 8; m++) {
    int row = wr + m * 16 + lrow;
    aoff[m] = row * 64 + ((lk ^ ((row >> 1) & 3)) << 4);
  }
#pragma unroll
  for (int n = 0; n < 4; n++) {
    int col = wc + n * 16 + lrow;
    boff[n] = col * 64 + ((lk ^ ((col >> 1) & 3)) << 4);
  }

  f32x4 acc[8][4];
#pragma unroll
  for (int n = 0; n < 4; n++) {
    float bv = bias[bcol + wc + n * 16 + lrow];
#pragma unroll
    for (int m = 0; m < 8; m++) acc[m][n] = (f32x4){bv, bv, bv, bv};
  }

#define STAGE_G(kt, slot)                                                  \
  {                                                                        \
    char* asb = (char*)As + (slot) * 16384 + w * 1024;                     \
    char* bsb = (char*)Bs + (slot) * 8192 + w * 1024;                      \
    gload16(ag0 + (kt) * 32,          asb);                                \
    gload16(ag0 + (kt) * 32 + 65536,  asb + 4096);                         \
    gload16(ag0 + (kt) * 32 + 131072, asb + 8192);                         \
    gload16(ag0 + (kt) * 32 + 196608, asb + 12288);                        \
    gload16(bg0 + (kt) * 32,          bsb);                                \
    gload16(bg0 + (kt) * 32 + 65536,  bsb + 4096);                         \
  }

  STAGE_G(0, 0)
  STAGE_G(1, 1)
  asm volatile("s_waitcnt vmcnt(6)" ::: "memory");
  __builtin_amdgcn_s_barrier();
  __builtin_amdgcn_sched_barrier(0);

  int s0 = 0, s2 = 2;
#pragma unroll 1
  for (int kt = 0; kt < 32; kt++) {
    if (kt < 30) STAGE_G(kt + 2, s2)
    const char* ab = (const char*)As + s0 * 16384;
    const char* bb = (const char*)Bs + s0 * 8192;
    bf16x8 bfr[4];
#pragma unroll
    for (int n = 0; n < 4; n++) bfr[n] = *(const bf16x8*)(bb + boff[n]);
#pragma unroll
    for (int m = 0; m < 8; m++) {
      bf16x8 af = *(const bf16x8*)(ab + aoff[m]);
#pragma unroll
      for (int n = 0; n < 4; n++)
        acc[m][n] = mfma16(af, bfr[n], acc[m][n]);
    }
    if (kt < 31) {
      if (kt < 30) {
        asm volatile("s_waitcnt vmcnt(6)" ::: "memory");
      } else {
        asm volatile("s_waitcnt vmcnt(0)" ::: "memory");
      }
      __builtin_amdgcn_s_barrier();
      __builtin_amdgcn_sched_barrier(0);
    }
    s0 = (s0 == 2) ? 0 : s0 + 1;
    s2 = (s2 == 2) ? 0 : s2 + 1;
  }
#undef STAGE_G

  if (mode == 3) {
    float* C = (float*)outp;
#pragma unroll
    for (int m = 0; m < 8; m++) {
      int r = brow + wr + m * 16 + 4 * lk;
#pragma unroll
      for (int n = 0; n < 4; n++) {
        int c = bcol + wc + n * 16 + lrow;
#pragma unroll
        for (int j = 0; j < 4; j++) C[(r + j) * 1024 + c] = acc[m][n][j];
      }
    }
  }
}

__global__ __launch_bounds__(256, 2) void k_gemm(const unsigned short* __restrict__ A,
                                                 const unsigned short* __restrict__ Bt,
                                                 const float* __restrict__ bias,
                                                 void* __restrict__ outp,
                                                 int mode, float oscale) {
  __shared__ unsigned short As[24576];
  __shared__ unsigned short Bs[12288];
  gemm_body(A, Bt, bias, outp, mode, oscale, blockIdx.x * 256, blockIdx.y * 128, As, Bs);
}

// ---------------- flash attention (r16 verbatim: staged KVBLK=128, XCD-local grid) ----------------
__global__ __launch_bounds__(256, 2) void k_attn(const unsigned short* __restrict__ Qh,
                                                 const unsigned short* __restrict__ Kh,
                                                 const unsigned short* __restrict__ Vth,
                                                 unsigned short* __restrict__ Y) {
  __shared__ unsigned short Ks[16384];
  __shared__ unsigned short Vs[16384];
  __shared__ unsigned short Ps[8192];

  const int tid = threadIdx.x, l = tid & 63, w = tid >> 6;
  const int lrow = l & 15, lk = l >> 4;
  const int bh = blockIdx.x;
  const int pp = blockIdx.y;

  const unsigned short* Qb = Qh + bh * 65536;
  const unsigned short* Kb = Kh + bh * 65536;
  const unsigned short* Vb = Vth + bh * 65536;

  bf16x8 ones;
#pragma unroll
  for (int j = 0; j < 8; j++) ones[j] = (__bf16)1.0f;

  const int krl = l >> 3;
  const int kgp = l & 7;
  const unsigned short* kgsrc = Kb + (w * 32 + krl) * 64 + ((kgp ^ krl) * 8);
  const int vrl = l >> 4;
  const int vgp = l & 15;
  const int vr0 = w * 16 + 0 * 4 + vrl;
  const int vr1 = w * 16 + 1 * 4 + vrl;
  const int vr2 = w * 16 + 2 * 4 + vrl;
  const int vr3 = w * 16 + 3 * 4 + vrl;
  const int voff0 = vr0 * 1024 + ((vgp ^ (vr0 & 15)) * 8);
  const int voff1 = vr1 * 1024 + ((vgp ^ (vr1 & 15)) * 8);
  const int voff2 = vr2 * 1024 + ((vgp ^ (vr2 & 15)) * 8);
  const int voff3 = vr3 * 1024 + ((vgp ^ (vr3 & 15)) * 8);

  char* pw = (char*)Ps + w * 4096;

  const int b = bh >> 4, h = bh & 15;

#pragma unroll 1
  for (int hp = 0; hp < 2; hp++) {
    const int qi = hp == 0 ? (7 - pp) : pp;
    const int qw = qi * 128 + w * 32;
    const int qmax = qw + 31;

    bf16x8 qf[2][2];
#pragma unroll
    for (int qn = 0; qn < 2; qn++) {
      const unsigned short* qp = Qb + (qw + qn * 16 + lrow) * 64 + lk * 8;
      qf[qn][0] = *(const bf16x8*)qp;
      qf[qn][1] = *(const bf16x8*)(qp + 32);
    }

    float mm[2];
    f32x4 lsum[2], yacc[2][4];
#pragma unroll
    for (int qn = 0; qn < 2; qn++) {
      mm[qn] = MASKNEG;
      lsum[qn] = (f32x4){0.f, 0.f, 0.f, 0.f};
#pragma unroll
      for (int ef = 0; ef < 4; ef++) yacc[qn][ef] = (f32x4){0.f, 0.f, 0.f, 0.f};
    }

    const int nt = qi + 1;

    {
      char* kb = (char*)Ks + w * 4096;
      char* vb2 = (char*)Vs + w * 4096;
      gload16(kgsrc + 0,    kb);
      gload16(kgsrc + 512,  kb + 1024);
      gload16(kgsrc + 1024, kb + 2048);
      gload16(kgsrc + 1536, kb + 3072);
      gload16(Vb + voff0, vb2);
      gload16(Vb + voff1, vb2 + 1024);
      gload16(Vb + voff2, vb2 + 2048);
      gload16(Vb + voff3, vb2 + 3072);
    }
    __syncthreads();

#pragma unroll 1
    for (int t = 0; t < nt; t++) {
      const int z0 = t * 128;
      const int cur = t & 1;
      if (t < nt - 1) {
        const int zn = (t + 1) * 128;
        char* kb = (char*)Ks + (cur ^ 1) * 16384 + w * 4096;
        char* vb2 = (char*)Vs + (cur ^ 1) * 16384 + w * 4096;
        const unsigned short* kgt = kgsrc + zn * 64;
        gload16(kgt + 0,    kb);
        gload16(kgt + 512,  kb + 1024);
        gload16(kgt + 1024, kb + 2048);
        gload16(kgt + 1536, kb + 3072);
        gload16(Vb + voff0 + zn, vb2);
        gload16(Vb + voff1 + zn, vb2 + 1024);
        gload16(Vb + voff2 + zn, vb2 + 2048);
        gload16(Vb + voff3 + zn, vb2 + 3072);
      }

      if (z0 <= qmax) {
        const char* kbase = (const char*)Ks + cur * 16384;
        const char* vbase = (const char*)Vs + cur * 16384;

        f32x4 s[2][8];
#pragma unroll
        for (int qn = 0; qn < 2; qn++)
#pragma unroll
          for (int zf = 0; zf < 8; zf++) s[qn][zf] = (f32x4){0.f, 0.f, 0.f, 0.f};
#pragma unroll
        for (int zf = 0; zf < 8; zf++) {
          int zr = zf * 16 + lrow;
#pragma unroll
          for (int kf = 0; kf < 2; kf++) {
            bf16x8 kfr = *(const bf16x8*)(kbase + zr * 128 + (((kf * 4 + lk) ^ (zr & 7)) << 4));
            s[0][zf] = mfma16(kfr, qf[0][kf], s[0][zf]);
            s[1][zf] = mfma16(kfr, qf[1][kf], s[1][zf]);
          }
        }

        if (z0 + 127 > qw) {
#pragma unroll
          for (int qn = 0; qn < 2; qn++) {
            int qg = qw + qn * 16 + lrow;
#pragma unroll
            for (int zf = 0; zf < 8; zf++) {
              int zb = z0 + zf * 16 + 4 * lk;
#pragma unroll
              for (int j = 0; j < 4; j++)
                if (zb + j > qg) s[qn][zf][j] = MASKNEG;
            }
          }
        }

#pragma unroll
        for (int qn = 0; qn < 2; qn++) {
          f32x4 r4 = s[qn][0];
#pragma unroll
          for (int zf = 1; zf < 8; zf++)
#pragma unroll
            for (int j = 0; j < 4; j++) r4[j] = fmaxf(r4[j], s[qn][zf][j]);
          float rm = fmaxf(fmaxf(r4[0], r4[1]), fmaxf(r4[2], r4[3]));
          rm = fmaxf(rm, __shfl_xor(rm, 16));
          rm = fmaxf(rm, __shfl_xor(rm, 32));

          if (__any(rm > mm[qn] + 8.f)) {
            float mn = fmaxf(mm[qn], rm);
            float a = __builtin_amdgcn_exp2f(mm[qn] - mn);
            mm[qn] = mn;
            f32x4 av;
#pragma unroll
            for (int j = 0; j < 4; j++)
              av[j] = __shfl(a, (l & 48) | (lk * 4 + j));
            lsum[qn] *= av;
#pragma unroll
            for (int ef = 0; ef < 4; ef++) yacc[qn][ef] *= av;
          }
          float mk = mm[qn];
#pragma unroll
          for (int zf = 0; zf < 8; zf++)
#pragma unroll
            for (int j = 0; j < 4; j++)
              s[qn][zf][j] = __builtin_amdgcn_exp2f(s[qn][zf][j] - mk);
        }

#pragma unroll
        for (int hf = 0; hf < 2; hf++) {
          if (z0 + hf * 64 <= qmax) {
#pragma unroll
            for (int qn = 0; qn < 2; qn++) {
              int q = qn * 16 + lrow;
              char* rowp = pw + q * 128;
#pragma unroll
              for (int zf2 = 0; zf2 < 4; zf2++) {
                int zfg = hf * 4 + zf2;
                u16x4 o;
#pragma unroll
                for (int j = 0; j < 4; j++) o[j] = f2bf(s[qn][zfg][j]);
                int g = zf2 * 2 + (lk >> 1);
                *(u16x4*)(rowp + ((g ^ (q & 7)) << 4) + (lk & 1) * 8) = o;
              }
            }

            asm volatile("s_waitcnt lgkmcnt(0)" ::: "memory");
            __builtin_amdgcn_sched_barrier(0);

            bf16x8 pf[2][2];
#pragma unroll
            for (int qn = 0; qn < 2; qn++)
#pragma unroll
              for (int kf = 0; kf < 2; kf++)
                pf[qn][kf] = *(const bf16x8*)(pw + (qn * 16 + lrow) * 128 + (((kf * 4 + lk) ^ (lrow & 7)) << 4));

#pragma unroll
            for (int qn = 0; qn < 2; qn++)
#pragma unroll
              for (int kf = 0; kf < 2; kf++)
                lsum[qn] = mfma16(pf[qn][kf], ones, lsum[qn]);

#pragma unroll
            for (int ef = 0; ef < 4; ef++) {
              int er = ef * 16 + lrow;
#pragma unroll
              for (int kf = 0; kf < 2; kf++) {
                int g = hf * 8 + kf * 4 + lk;
                bf16x8 vf = *(const bf16x8*)(vbase + er * 256 + ((g ^ (er & 15)) << 4));
                yacc[0][ef] = mfma16(pf[0][kf], vf, yacc[0][ef]);
                yacc[1][ef] = mfma16(pf[1][kf], vf, yacc[1][ef]);
              }
            }
          }
        }
      }

      __syncthreads();
    }

#pragma unroll
    for (int qn = 0; qn < 2; qn++) {
      f32x4 rinv;
#pragma unroll
      for (int j = 0; j < 4; j++) rinv[j] = 1.0f / lsum[qn][j];
#pragma unroll
      for (int ef = 0; ef < 4; ef++) {
        int col = h * 64 + ef * 16 + lrow;
#pragma unroll
        for (int j = 0; j < 4; j++) {
          int x = qw + qn * 16 + lk * 4 + j;
          Y[(b * 1024 + x) * 1024 + col] = f2bf(yacc[qn][ef][j] * rinv[j]);
        }
      }
    }
  }
}

// ---------------- launch ----------------
extern "C" void kernel_launch(void* const* d_in, const int* in_sizes, int n_in,
                              void* d_out, int out_size, void* d_ws, size_t ws_size,
                              hipStream_t stream) {
  const float* x  = (const float*)d_in[0];
  const float* z  = (const float*)d_in[1];
  const float* Wq = (const float*)d_in[2];
  const float* bq = (const float*)d_in[3];
  const float* Wk = (const float*)d_in[4];
  const float* bk = (const float*)d_in[5];
  const float* Wv = (const float*)d_in[6];
  const float* bv = (const float*)d_in[7];
  const float* Wp = (const float*)d_in[8];
  const float* bp = (const float*)d_in[9];
  (void)in_sizes; (void)n_in; (void)out_size; (void)ws_size;

  char* ws = (char*)d_ws;
  unsigned short* Xb  = (unsigned short*)(ws + 0);
  unsigned short* Zb  = (unsigned short*)(ws + 16777216);
  unsigned short* Wqt = (unsigned short*)(ws + 33554432);  // Wqt/Wkt/Wvt contiguous = Wqkv
  unsigned short* Wkt = (unsigned short*)(ws + 35651584);
  unsigned short* Wvt = (unsigned short*)(ws + 37748736);
  unsigned short* Wpt = (unsigned short*)(ws + 39845888);
  unsigned short* Qp  = (unsigned short*)(ws + 41943040);
  unsigned short* Kp  = (unsigned short*)(ws + 58720256);
  unsigned short* Vtp = (unsigned short*)(ws + 75497472);

  k_cvt2<<<dim3(2048), dim3(256), 0, stream>>>(x, z, Xb);
  k_pack<<<dim3(16, 16, 4), dim3(256), 0, stream>>>(Wq, Wk, Wv, Wp, Wqt, Wkt, Wvt, Wpt);

  k_gemm_qkv8<<<dim3(32, 12), dim3(512), 0, stream>>>(Xb, Zb, Wqt, bq, bk, bv, Qp, Kp, Vtp);

  k_attn<<<dim3(128, 4), dim3(256), 0, stream>>>(Qp, Kp, Vtp, Xb /*Y*/);

  k_gemm<<<dim3(32, 8), dim3(256), 0, stream>>>(Xb, Wpt, bp, d_out, 3, 1.0f);
}

// Round 18
// 146.795 us; speedup vs baseline: 1.0432x; 1.0432x over previous
//
#include <hip/hip_runtime.h>
#include <stdint.h>

// Pipeline: cvt x,z -> bf16; pack weights; fused QKV GEMM (r12/r16-validated 256x128
// ring, counted vmcnt(6), 72KB LDS); flash attention (staged KVBLK=128, swapped QK^T,
// in-lane softmax, defer-max, XCD-local grid, NATIVE bf16 casts in P-path); output
// GEMM -> f32.
// v_cvt_pk_bf16_f32 INLINE ASM is BANNED (NaN culprit; compiler-emitted converts are OK).
// Direct-from-global K/V BANNED (r15: latency-bound scatter). Phased GEMM schedules
// closed out (r13/r17: both regressed vs ring).
// B=8 TX=TZ=1024 DX=DZ=1024 DATT=DMID=64 H=16 DOUT=1024.

typedef float    f32x4  __attribute__((ext_vector_type(4)));
typedef __bf16   bf16x8 __attribute__((ext_vector_type(8)));
typedef unsigned short u16x4 __attribute__((ext_vector_type(4)));
typedef unsigned short u16x8 __attribute__((ext_vector_type(8)));

#define MASKNEG (-3.0e38f)
#define QSCALE_F (0.125f * 1.4426950408889634f)

__device__ __forceinline__ unsigned short f2bf(float f) {
  unsigned int u = __float_as_uint(f);
  u += 0x7fffu + ((u >> 16) & 1u);   // RNE (software)
  return (unsigned short)(u >> 16);
}

// native hardware convert (compiler may fold pairs into v_cvt_pk_bf16_f32)
__device__ __forceinline__ unsigned short f2bf_hw(float f) {
  __bf16 h = (__bf16)f;
  return *(unsigned short*)&h;
}

__device__ __forceinline__ void gload16(const void* g, void* s) {
  const __attribute__((address_space(1))) unsigned int* gp =
      (const __attribute__((address_space(1))) unsigned int*)(uintptr_t)g;
  __attribute__((address_space(3))) unsigned int* lp =
      (__attribute__((address_space(3))) unsigned int*)(unsigned int)(uintptr_t)s;
  __builtin_amdgcn_global_load_lds(gp, lp, 16, 0, 0);
}

__device__ __forceinline__ f32x4 mfma16(bf16x8 a, bf16x8 b, f32x4 c) {
  return __builtin_amdgcn_mfma_f32_16x16x32_bf16(a, b, c, 0, 0, 0);
}

// ---------------- prep kernels (r12 verbatim) ----------------

__global__ __launch_bounds__(256) void k_cvt2(const float* __restrict__ x,
                                              const float* __restrict__ z,
                                              unsigned short* __restrict__ out) {
  int i = blockIdx.x * 256 + threadIdx.x;
  const int stride = gridDim.x * 256;
  for (; i < 2097152; i += stride) {
    const float* in = (i < 1048576) ? (x + (size_t)i * 8) : (z + (size_t)(i - 1048576) * 8);
    const f32x4* p = (const f32x4*)in;
    f32x4 a = p[0], b = p[1];
    u16x8 o;
    o[0] = f2bf(a[0]); o[1] = f2bf(a[1]); o[2] = f2bf(a[2]); o[3] = f2bf(a[3]);
    o[4] = f2bf(b[0]); o[5] = f2bf(b[1]); o[6] = f2bf(b[2]); o[7] = f2bf(b[3]);
    *(u16x8*)(out + (size_t)i * 8) = o;
  }
}

__global__ __launch_bounds__(256) void k_pack(const float* __restrict__ Wq,
                                              const float* __restrict__ Wk,
                                              const float* __restrict__ Wv,
                                              const float* __restrict__ Wp,
                                              unsigned short* __restrict__ Oq,
                                              unsigned short* __restrict__ Ok,
                                              unsigned short* __restrict__ Ov,
                                              unsigned short* __restrict__ Op) {
  __shared__ float tile[64][65];
  const int t = threadIdx.x;
  const int zid = blockIdx.z;
  if (zid < 3) {
    const float* W = zid == 0 ? Wq : (zid == 1 ? Wk : Wv);
    unsigned short* O = zid == 0 ? Oq : (zid == 1 ? Ok : Ov);
    const int h = blockIdx.x, d0 = blockIdx.y * 64;
    const int ee = t & 63, r0 = t >> 6;
#pragma unroll
    for (int dd = r0; dd < 64; dd += 4)
      tile[dd][ee] = W[(h * 1024 + d0 + dd) * 64 + ee];
    __syncthreads();
    const int d = t & 63, e0 = t >> 6;
#pragma unroll
    for (int e = e0; e < 64; e += 4)
      O[(h * 64 + e) * 1024 + d0 + d] = f2bf(tile[d][e]);
  } else {
    const int k0 = blockIdx.x * 64, n0 = blockIdx.y * 64;
    const int nn = t & 63, r0 = t >> 6;
#pragma unroll
    for (int kk = r0; kk < 64; kk += 4)
      tile[kk][nn] = Wp[(k0 + kk) * 1024 + n0 + nn];
    __syncthreads();
    const int kk = t & 63, e0 = t >> 6;
#pragma unroll
    for (int n2 = e0; n2 < 64; n2 += 4)
      Op[(n0 + n2) * 1024 + k0 + kk] = f2bf(tile[kk][n2]);
  }
}

// ---------------- GEMM body: C[256x128 tile] = A * Bt^T + bias (r12 verbatim) ----------------
__device__ __forceinline__ void gemm_body(const unsigned short* __restrict__ A,
                                          const unsigned short* __restrict__ Bt,
                                          const float* __restrict__ bias,
                                          void* __restrict__ outp,
                                          int mode, float oscale,
                                          int brow, int bcol,
                                          unsigned short* As, unsigned short* Bs) {
  const int tid = threadIdx.x;
  const int l = tid & 63, w = tid >> 6;
  const int lrow = l & 15, lk = l >> 4;
  const int wr = (w >> 1) * 128, wc = (w & 1) * 64;

  const int arow = tid >> 2;
  const int asrc = ((tid & 3) ^ ((arow >> 1) & 3)) * 8;
  const unsigned short* ag0 = A + (size_t)(brow + arow) * 1024 + asrc;
  const unsigned short* bg0 = Bt + (size_t)(bcol + arow) * 1024 + asrc;

  int aoff[8], boff[4];
#pragma unroll
  for (int m = 0; m < 8; m++) {
    int row = wr + m * 16 + lrow;
    aoff[m] = row * 64 + ((lk ^ ((row >> 1) & 3)) << 4);
  }
#pragma unroll
  for (int n = 0; n < 4; n++) {
    int col = wc + n * 16 + lrow;
    boff[n] = col * 64 + ((lk ^ ((col >> 1) & 3)) << 4);
  }

  f32x4 acc[8][4];
#pragma unroll
  for (int n = 0; n < 4; n++) {
    float bv = bias[bcol + wc + n * 16 + lrow];
#pragma unroll
    for (int m = 0; m < 8; m++) acc[m][n] = (f32x4){bv, bv, bv, bv};
  }

#define STAGE_G(kt, slot)                                                  \
  {                                                                        \
    char* asb = (char*)As + (slot) * 16384 + w * 1024;                     \
    char* bsb = (char*)Bs + (slot) * 8192 + w * 1024;                      \
    gload16(ag0 + (kt) * 32,          asb);                                \
    gload16(ag0 + (kt) * 32 + 65536,  asb + 4096);                         \
    gload16(ag0 + (kt) * 32 + 131072, asb + 8192);                         \
    gload16(ag0 + (kt) * 32 + 196608, asb + 12288);                        \
    gload16(bg0 + (kt) * 32,          bsb);                                \
    gload16(bg0 + (kt) * 32 + 65536,  bsb + 4096);                         \
  }

  STAGE_G(0, 0)
  STAGE_G(1, 1)
  asm volatile("s_waitcnt vmcnt(6)" ::: "memory");
  __builtin_amdgcn_s_barrier();
  __builtin_amdgcn_sched_barrier(0);

  int s0 = 0, s2 = 2;
#pragma unroll 1
  for (int kt = 0; kt < 32; kt++) {
    if (kt < 30) STAGE_G(kt + 2, s2)
    const char* ab = (const char*)As + s0 * 16384;
    const char* bb = (const char*)Bs + s0 * 8192;
    bf16x8 bfr[4];
#pragma unroll
    for (int n = 0; n < 4; n++) bfr[n] = *(const bf16x8*)(bb + boff[n]);
#pragma unroll
    for (int m = 0; m < 8; m++) {
      bf16x8 af = *(const bf16x8*)(ab + aoff[m]);
#pragma unroll
      for (int n = 0; n < 4; n++)
        acc[m][n] = mfma16(af, bfr[n], acc[m][n]);
    }
    if (kt < 31) {
      if (kt < 30) {
        asm volatile("s_waitcnt vmcnt(6)" ::: "memory");
      } else {
        asm volatile("s_waitcnt vmcnt(0)" ::: "memory");
      }
      __builtin_amdgcn_s_barrier();
      __builtin_amdgcn_sched_barrier(0);
    }
    s0 = (s0 == 2) ? 0 : s0 + 1;
    s2 = (s2 == 2) ? 0 : s2 + 1;
  }
#undef STAGE_G

  if (mode == 0) {
    unsigned short* C = (unsigned short*)outp;
#pragma unroll
    for (int m = 0; m < 8; m++) {
      int r = brow + wr + m * 16 + 4 * lk;
#pragma unroll
      for (int n = 0; n < 4; n++) {
        int c = bcol + wc + n * 16 + lrow;
        unsigned short* p = C + ((r >> 10) * 16 + (c >> 6)) * 65536 + (r & 1023) * 64 + (c & 63);
#pragma unroll
        for (int j = 0; j < 4; j++) p[j * 64] = f2bf(acc[m][n][j] * oscale);
      }
    }
  } else if (mode == 2) {
    unsigned short* C = (unsigned short*)outp;
#pragma unroll
    for (int m = 0; m < 8; m++) {
      int r = brow + wr + m * 16 + 4 * lk;
#pragma unroll
      for (int n = 0; n < 4; n++) {
        int c = bcol + wc + n * 16 + lrow;
        u16x4 o;
#pragma unroll
        for (int j = 0; j < 4; j++) o[j] = f2bf(acc[m][n][j]);
        *(u16x4*)(C + ((r >> 10) * 16 + (c >> 6)) * 65536 + (c & 63) * 1024 + (r & 1023)) = o;
      }
    }
  } else {
    float* C = (float*)outp;
#pragma unroll
    for (int m = 0; m < 8; m++) {
      int r = brow + wr + m * 16 + 4 * lk;
#pragma unroll
      for (int n = 0; n < 4; n++) {
        int c = bcol + wc + n * 16 + lrow;
#pragma unroll
        for (int j = 0; j < 4; j++) C[(r + j) * 1024 + c] = acc[m][n][j];
      }
    }
  }
}

__global__ __launch_bounds__(256, 2) void k_gemm_qkv(const unsigned short* __restrict__ Xb,
                                                     const unsigned short* __restrict__ Zb,
                                                     const unsigned short* __restrict__ Wqkv,
                                                     const float* __restrict__ bq,
                                                     const float* __restrict__ bk,
                                                     const float* __restrict__ bv,
                                                     unsigned short* __restrict__ Qp,
                                                     unsigned short* __restrict__ Kp,
                                                     unsigned short* __restrict__ Vtp) {
  __shared__ unsigned short As[24576];
  __shared__ unsigned short Bs[12288];
  const int brow = blockIdx.x * 256;
  const int cg = blockIdx.y;
  const int seg = cg >> 3;
  const int bcol = (cg & 7) * 128;
  const unsigned short* A = (seg == 0) ? Xb : Zb;
  const unsigned short* Bt = Wqkv + (size_t)seg * 1048576;
  const float* bias = (seg == 0) ? bq : (seg == 1 ? bk : bv);
  void* outp = (seg == 0) ? (void*)Qp : (seg == 1 ? (void*)Kp : (void*)Vtp);
  const int mode = (seg == 2) ? 2 : 0;
  const float oscale = (seg == 0) ? QSCALE_F : 1.0f;
  gemm_body(A, Bt, bias, outp, mode, oscale, brow, bcol, As, Bs);
}

__global__ __launch_bounds__(256, 2) void k_gemm(const unsigned short* __restrict__ A,
                                                 const unsigned short* __restrict__ Bt,
                                                 const float* __restrict__ bias,
                                                 void* __restrict__ outp,
                                                 int mode, float oscale) {
  __shared__ unsigned short As[24576];
  __shared__ unsigned short Bs[12288];
  gemm_body(A, Bt, bias, outp, mode, oscale, blockIdx.x * 256, blockIdx.y * 128, As, Bs);
}

// ---------------- flash attention (r16 body; native bf16 casts in P-path) ----------------
// grid (128, 4): bh = blockIdx.x, pp = blockIdx.y -> id%8 = bh%8: XCD-local K/V (4 MB/XCD).
__global__ __launch_bounds__(256, 2) void k_attn(const unsigned short* __restrict__ Qh,
                                                 const unsigned short* __restrict__ Kh,
                                                 const unsigned short* __restrict__ Vth,
                                                 unsigned short* __restrict__ Y) {
  __shared__ unsigned short Ks[16384];  // 2 x (128 z x 64 d) swizzled, 32 KB
  __shared__ unsigned short Vs[16384];  // 2 x (64 e x 128 z) swizzled, 32 KB
  __shared__ unsigned short Ps[8192];   // 4 waves x (32 q x 64 z) swizzled, 16 KB

  const int tid = threadIdx.x, l = tid & 63, w = tid >> 6;
  const int lrow = l & 15, lk = l >> 4;
  const int bh = blockIdx.x;
  const int pp = blockIdx.y;

  const unsigned short* Qb = Qh + bh * 65536;
  const unsigned short* Kb = Kh + bh * 65536;
  const unsigned short* Vb = Vth + bh * 65536;

  bf16x8 ones;
#pragma unroll
  for (int j = 0; j < 8; j++) ones[j] = (__bf16)1.0f;

  const int krl = l >> 3;
  const int kgp = l & 7;
  const unsigned short* kgsrc = Kb + (w * 32 + krl) * 64 + ((kgp ^ krl) * 8);
  const int vrl = l >> 4;
  const int vgp = l & 15;
  const int vr0 = w * 16 + 0 * 4 + vrl;
  const int vr1 = w * 16 + 1 * 4 + vrl;
  const int vr2 = w * 16 + 2 * 4 + vrl;
  const int vr3 = w * 16 + 3 * 4 + vrl;
  const int voff0 = vr0 * 1024 + ((vgp ^ (vr0 & 15)) * 8);
  const int voff1 = vr1 * 1024 + ((vgp ^ (vr1 & 15)) * 8);
  const int voff2 = vr2 * 1024 + ((vgp ^ (vr2 & 15)) * 8);
  const int voff3 = vr3 * 1024 + ((vgp ^ (vr3 & 15)) * 8);

  char* pw = (char*)Ps + w * 4096;

  const int b = bh >> 4, h = bh & 15;

#pragma unroll 1
  for (int hp = 0; hp < 2; hp++) {
    const int qi = hp == 0 ? (7 - pp) : pp;
    const int qw = qi * 128 + w * 32;
    const int qmax = qw + 31;

    bf16x8 qf[2][2];
#pragma unroll
    for (int qn = 0; qn < 2; qn++) {
      const unsigned short* qp = Qb + (qw + qn * 16 + lrow) * 64 + lk * 8;
      qf[qn][0] = *(const bf16x8*)qp;
      qf[qn][1] = *(const bf16x8*)(qp + 32);
    }

    float mm[2];
    f32x4 lsum[2], yacc[2][4];
#pragma unroll
    for (int qn = 0; qn < 2; qn++) {
      mm[qn] = MASKNEG;
      lsum[qn] = (f32x4){0.f, 0.f, 0.f, 0.f};
#pragma unroll
      for (int ef = 0; ef < 4; ef++) yacc[qn][ef] = (f32x4){0.f, 0.f, 0.f, 0.f};
    }

    const int nt = qi + 1;

    {
      char* kb = (char*)Ks + w * 4096;
      char* vb2 = (char*)Vs + w * 4096;
      gload16(kgsrc + 0,    kb);
      gload16(kgsrc + 512,  kb + 1024);
      gload16(kgsrc + 1024, kb + 2048);
      gload16(kgsrc + 1536, kb + 3072);
      gload16(Vb + voff0, vb2);
      gload16(Vb + voff1, vb2 + 1024);
      gload16(Vb + voff2, vb2 + 2048);
      gload16(Vb + voff3, vb2 + 3072);
    }
    __syncthreads();

#pragma unroll 1
    for (int t = 0; t < nt; t++) {
      const int z0 = t * 128;
      const int cur = t & 1;
      if (t < nt - 1) {
        const int zn = (t + 1) * 128;
        char* kb = (char*)Ks + (cur ^ 1) * 16384 + w * 4096;
        char* vb2 = (char*)Vs + (cur ^ 1) * 16384 + w * 4096;
        const unsigned short* kgt = kgsrc + zn * 64;
        gload16(kgt + 0,    kb);
        gload16(kgt + 512,  kb + 1024);
        gload16(kgt + 1024, kb + 2048);
        gload16(kgt + 1536, kb + 3072);
        gload16(Vb + voff0 + zn, vb2);
        gload16(Vb + voff1 + zn, vb2 + 1024);
        gload16(Vb + voff2 + zn, vb2 + 2048);
        gload16(Vb + voff3 + zn, vb2 + 3072);
      }

      if (z0 <= qmax) {
        const char* kbase = (const char*)Ks + cur * 16384;
        const char* vbase = (const char*)Vs + cur * 16384;

        // S^T: lane holds S[z = z0 + zf*16 + 4*lk + j][q = qw + qn*16 + lrow]
        f32x4 s[2][8];
#pragma unroll
        for (int qn = 0; qn < 2; qn++)
#pragma unroll
          for (int zf = 0; zf < 8; zf++) s[qn][zf] = (f32x4){0.f, 0.f, 0.f, 0.f};
#pragma unroll
        for (int zf = 0; zf < 8; zf++) {
          int zr = zf * 16 + lrow;
#pragma unroll
          for (int kf = 0; kf < 2; kf++) {
            bf16x8 kfr = *(const bf16x8*)(kbase + zr * 128 + (((kf * 4 + lk) ^ (zr & 7)) << 4));
            s[0][zf] = mfma16(kfr, qf[0][kf], s[0][zf]);
            s[1][zf] = mfma16(kfr, qf[1][kf], s[1][zf]);
          }
        }

        if (z0 + 127 > qw) {   // diagonal overlap: mask z > q
#pragma unroll
          for (int qn = 0; qn < 2; qn++) {
            int qg = qw + qn * 16 + lrow;
#pragma unroll
            for (int zf = 0; zf < 8; zf++) {
              int zb = z0 + zf * 16 + 4 * lk;
#pragma unroll
              for (int j = 0; j < 4; j++)
                if (zb + j > qg) s[qn][zf][j] = MASKNEG;
            }
          }
        }

        // in-lane softmax: 31 fmax + 2 shfls; defer-max THR=8 (log2 domain)
#pragma unroll
        for (int qn = 0; qn < 2; qn++) {
          f32x4 r4 = s[qn][0];
#pragma unroll
          for (int zf = 1; zf < 8; zf++)
#pragma unroll
            for (int j = 0; j < 4; j++) r4[j] = fmaxf(r4[j], s[qn][zf][j]);
          float rm = fmaxf(fmaxf(r4[0], r4[1]), fmaxf(r4[2], r4[3]));
          rm = fmaxf(rm, __shfl_xor(rm, 16));
          rm = fmaxf(rm, __shfl_xor(rm, 32));

          if (__any(rm > mm[qn] + 8.f)) {
            float mn = fmaxf(mm[qn], rm);
            float a = __builtin_amdgcn_exp2f(mm[qn] - mn);  // <= 0 arg
            mm[qn] = mn;
            f32x4 av;
#pragma unroll
            for (int j = 0; j < 4; j++)
              av[j] = __shfl(a, (l & 48) | (lk * 4 + j));
            lsum[qn] *= av;
#pragma unroll
            for (int ef = 0; ef < 4; ef++) yacc[qn][ef] *= av;
          }
          float mk = mm[qn];
#pragma unroll
          for (int zf = 0; zf < 8; zf++)
#pragma unroll
            for (int j = 0; j < 4; j++)
              s[qn][zf][j] = __builtin_amdgcn_exp2f(s[qn][zf][j] - mk);  // <= 2^8
        }

        // PV in two 64-z halves
#pragma unroll
        for (int hf = 0; hf < 2; hf++) {
          if (z0 + hf * 64 <= qmax) {
            // P^T -> P[q][z] rows in LDS (vectorized u16x4; NATIVE bf16 casts)
#pragma unroll
            for (int qn = 0; qn < 2; qn++) {
              int q = qn * 16 + lrow;
              char* rowp = pw + q * 128;
#pragma unroll
              for (int zf2 = 0; zf2 < 4; zf2++) {
                int zfg = hf * 4 + zf2;
                u16x4 o;
#pragma unroll
                for (int j = 0; j < 4; j++) o[j] = f2bf_hw(s[qn][zfg][j]);
                int g = zf2 * 2 + (lk >> 1);
                *(u16x4*)(rowp + ((g ^ (q & 7)) << 4) + (lk & 1) * 8) = o;
              }
            }

            asm volatile("s_waitcnt lgkmcnt(0)" ::: "memory");
            __builtin_amdgcn_sched_barrier(0);

            bf16x8 pf[2][2];
#pragma unroll
            for (int qn = 0; qn < 2; qn++)
#pragma unroll
              for (int kf = 0; kf < 2; kf++)
                pf[qn][kf] = *(const bf16x8*)(pw + (qn * 16 + lrow) * 128 + (((kf * 4 + lk) ^ (lrow & 7)) << 4));

#pragma unroll
            for (int qn = 0; qn < 2; qn++)
#pragma unroll
              for (int kf = 0; kf < 2; kf++)
                lsum[qn] = mfma16(pf[qn][kf], ones, lsum[qn]);

#pragma unroll
            for (int ef = 0; ef < 4; ef++) {
              int er = ef * 16 + lrow;
#pragma unroll
              for (int kf = 0; kf < 2; kf++) {
                int g = hf * 8 + kf * 4 + lk;
                bf16x8 vf = *(const bf16x8*)(vbase + er * 256 + ((g ^ (er & 15)) << 4));
                yacc[0][ef] = mfma16(pf[0][kf], vf, yacc[0][ef]);
                yacc[1][ef] = mfma16(pf[1][kf], vf, yacc[1][ef]);
              }
            }
          }
        }
      }

      __syncthreads();
    }

    // epilogue (native bf16 casts): q = qw + qn*16 + lk*4 + j, e = ef*16 + lrow
#pragma unroll
    for (int qn = 0; qn < 2; qn++) {
      f32x4 rinv;
#pragma unroll
      for (int j = 0; j < 4; j++) rinv[j] = 1.0f / lsum[qn][j];
#pragma unroll
      for (int ef = 0; ef < 4; ef++) {
        int col = h * 64 + ef * 16 + lrow;
#pragma unroll
        for (int j = 0; j < 4; j++) {
          int x = qw + qn * 16 + lk * 4 + j;
          Y[(b * 1024 + x) * 1024 + col] = f2bf_hw(yacc[qn][ef][j] * rinv[j]);
        }
      }
    }
  }
}

// ---------------- launch ----------------
extern "C" void kernel_launch(void* const* d_in, const int* in_sizes, int n_in,
                              void* d_out, int out_size, void* d_ws, size_t ws_size,
                              hipStream_t stream) {
  const float* x  = (const float*)d_in[0];
  const float* z  = (const float*)d_in[1];
  const float* Wq = (const float*)d_in[2];
  const float* bq = (const float*)d_in[3];
  const float* Wk = (const float*)d_in[4];
  const float* bk = (const float*)d_in[5];
  const float* Wv = (const float*)d_in[6];
  const float* bv = (const float*)d_in[7];
  const float* Wp = (const float*)d_in[8];
  const float* bp = (const float*)d_in[9];
  (void)in_sizes; (void)n_in; (void)out_size; (void)ws_size;

  char* ws = (char*)d_ws;
  unsigned short* Xb  = (unsigned short*)(ws + 0);
  unsigned short* Zb  = (unsigned short*)(ws + 16777216);
  unsigned short* Wqt = (unsigned short*)(ws + 33554432);  // Wqt/Wkt/Wvt contiguous = Wqkv
  unsigned short* Wkt = (unsigned short*)(ws + 35651584);
  unsigned short* Wvt = (unsigned short*)(ws + 37748736);
  unsigned short* Wpt = (unsigned short*)(ws + 39845888);
  unsigned short* Qp  = (unsigned short*)(ws + 41943040);
  unsigned short* Kp  = (unsigned short*)(ws + 58720256);
  unsigned short* Vtp = (unsigned short*)(ws + 75497472);

  k_cvt2<<<dim3(2048), dim3(256), 0, stream>>>(x, z, Xb);
  k_pack<<<dim3(16, 16, 4), dim3(256), 0, stream>>>(Wq, Wk, Wv, Wp, Wqt, Wkt, Wvt, Wpt);

  k_gemm_qkv<<<dim3(32, 24), dim3(256), 0, stream>>>(Xb, Zb, Wqt, bq, bk, bv, Qp, Kp, Vtp);

  k_attn<<<dim3(128, 4), dim3(256), 0, stream>>>(Qp, Kp, Vtp, Xb /*Y*/);

  k_gemm<<<dim3(32, 8), dim3(256), 0, stream>>>(Xb, Wpt, bp, d_out, 3, 1.0f);
}

// Round 19
// 146.332 us; speedup vs baseline: 1.0465x; 1.0032x over previous
//
#include <hip/hip_runtime.h>
#include <stdint.h>

// Pipeline: cvt x,z -> bf16; pack weights; fused QKV GEMM (256x128 tile, 2-slot dbuf,
// 48KB LDS -> 3 blocks/CU, grid 768 = one exact round); flash attention (staged
// KVBLK=128, swapped QK^T, in-lane softmax, defer-max, XCD-local grid, native bf16
// casts); output GEMM -> f32.
// v_cvt_pk_bf16_f32 INLINE ASM BANNED (NaN culprit; compiler-emitted converts OK).
// Direct-from-global K/V BANNED (r15). Phased GEMM schedules closed out (r13/r17).
// B=8 TX=TZ=1024 DX=DZ=1024 DATT=DMID=64 H=16 DOUT=1024.

typedef float    f32x4  __attribute__((ext_vector_type(4)));
typedef __bf16   bf16x8 __attribute__((ext_vector_type(8)));
typedef unsigned short u16x4 __attribute__((ext_vector_type(4)));
typedef unsigned short u16x8 __attribute__((ext_vector_type(8)));

#define MASKNEG (-3.0e38f)
#define QSCALE_F (0.125f * 1.4426950408889634f)

__device__ __forceinline__ unsigned short f2bf(float f) {
  unsigned int u = __float_as_uint(f);
  u += 0x7fffu + ((u >> 16) & 1u);   // RNE (software)
  return (unsigned short)(u >> 16);
}

// native hardware convert (compiler may fold pairs into v_cvt_pk_bf16_f32)
__device__ __forceinline__ unsigned short f2bf_hw(float f) {
  __bf16 h = (__bf16)f;
  return *(unsigned short*)&h;
}

__device__ __forceinline__ void gload16(const void* g, void* s) {
  const __attribute__((address_space(1))) unsigned int* gp =
      (const __attribute__((address_space(1))) unsigned int*)(uintptr_t)g;
  __attribute__((address_space(3))) unsigned int* lp =
      (__attribute__((address_space(3))) unsigned int*)(unsigned int)(uintptr_t)s;
  __builtin_amdgcn_global_load_lds(gp, lp, 16, 0, 0);
}

__device__ __forceinline__ f32x4 mfma16(bf16x8 a, bf16x8 b, f32x4 c) {
  return __builtin_amdgcn_mfma_f32_16x16x32_bf16(a, b, c, 0, 0, 0);
}

// ---------------- prep kernels (r12 verbatim) ----------------

__global__ __launch_bounds__(256) void k_cvt2(const float* __restrict__ x,
                                              const float* __restrict__ z,
                                              unsigned short* __restrict__ out) {
  int i = blockIdx.x * 256 + threadIdx.x;
  const int stride = gridDim.x * 256;
  for (; i < 2097152; i += stride) {
    const float* in = (i < 1048576) ? (x + (size_t)i * 8) : (z + (size_t)(i - 1048576) * 8);
    const f32x4* p = (const f32x4*)in;
    f32x4 a = p[0], b = p[1];
    u16x8 o;
    o[0] = f2bf(a[0]); o[1] = f2bf(a[1]); o[2] = f2bf(a[2]); o[3] = f2bf(a[3]);
    o[4] = f2bf(b[0]); o[5] = f2bf(b[1]); o[6] = f2bf(b[2]); o[7] = f2bf(b[3]);
    *(u16x8*)(out + (size_t)i * 8) = o;
  }
}

__global__ __launch_bounds__(256) void k_pack(const float* __restrict__ Wq,
                                              const float* __restrict__ Wk,
                                              const float* __restrict__ Wv,
                                              const float* __restrict__ Wp,
                                              unsigned short* __restrict__ Oq,
                                              unsigned short* __restrict__ Ok,
                                              unsigned short* __restrict__ Ov,
                                              unsigned short* __restrict__ Op) {
  __shared__ float tile[64][65];
  const int t = threadIdx.x;
  const int zid = blockIdx.z;
  if (zid < 3) {
    const float* W = zid == 0 ? Wq : (zid == 1 ? Wk : Wv);
    unsigned short* O = zid == 0 ? Oq : (zid == 1 ? Ok : Ov);
    const int h = blockIdx.x, d0 = blockIdx.y * 64;
    const int ee = t & 63, r0 = t >> 6;
#pragma unroll
    for (int dd = r0; dd < 64; dd += 4)
      tile[dd][ee] = W[(h * 1024 + d0 + dd) * 64 + ee];
    __syncthreads();
    const int d = t & 63, e0 = t >> 6;
#pragma unroll
    for (int e = e0; e < 64; e += 4)
      O[(h * 64 + e) * 1024 + d0 + d] = f2bf(tile[d][e]);
  } else {
    const int k0 = blockIdx.x * 64, n0 = blockIdx.y * 64;
    const int nn = t & 63, r0 = t >> 6;
#pragma unroll
    for (int kk = r0; kk < 64; kk += 4)
      tile[kk][nn] = Wp[(k0 + kk) * 1024 + n0 + nn];
    __syncthreads();
    const int kk = t & 63, e0 = t >> 6;
#pragma unroll
    for (int n2 = e0; n2 < 64; n2 += 4)
      Op[(n0 + n2) * 1024 + k0 + kk] = f2bf(tile[kk][n2]);
  }
}

// ---------------- GEMM body: C[256x128 tile] = A * Bt^T + bias ----------------
// 2-slot double buffer (48 KB LDS -> 3 blocks/CU): stage kt+1 at top into slot^1,
// compute slot, vmcnt(0)+barrier at bottom. Cross-block TLP (12 waves/CU) hides the
// drain (m114 mechanism). Geometry/swizzles/epilogues r12-verbatim.
__device__ __forceinline__ void gemm_body(const unsigned short* __restrict__ A,
                                          const unsigned short* __restrict__ Bt,
                                          const float* __restrict__ bias,
                                          void* __restrict__ outp,
                                          int mode, float oscale,
                                          int brow, int bcol,
                                          unsigned short* As, unsigned short* Bs) {
  const int tid = threadIdx.x;
  const int l = tid & 63, w = tid >> 6;
  const int lrow = l & 15, lk = l >> 4;
  const int wr = (w >> 1) * 128, wc = (w & 1) * 64;

  const int arow = tid >> 2;
  const int asrc = ((tid & 3) ^ ((arow >> 1) & 3)) * 8;
  const unsigned short* ag0 = A + (size_t)(brow + arow) * 1024 + asrc;
  const unsigned short* bg0 = Bt + (size_t)(bcol + arow) * 1024 + asrc;

  int aoff[8], boff[4];
#pragma unroll
  for (int m = 0; m < 8; m++) {
    int row = wr + m * 16 + lrow;
    aoff[m] = row * 64 + ((lk ^ ((row >> 1) & 3)) << 4);
  }
#pragma unroll
  for (int n = 0; n < 4; n++) {
    int col = wc + n * 16 + lrow;
    boff[n] = col * 64 + ((lk ^ ((col >> 1) & 3)) << 4);
  }

  f32x4 acc[8][4];
#pragma unroll
  for (int n = 0; n < 4; n++) {
    float bv = bias[bcol + wc + n * 16 + lrow];
#pragma unroll
    for (int m = 0; m < 8; m++) acc[m][n] = (f32x4){bv, bv, bv, bv};
  }

#define STAGE_G(kt, slot)                                                  \
  {                                                                        \
    char* asb = (char*)As + (slot) * 16384 + w * 1024;                     \
    char* bsb = (char*)Bs + (slot) * 8192 + w * 1024;                      \
    gload16(ag0 + (kt) * 32,          asb);                                \
    gload16(ag0 + (kt) * 32 + 65536,  asb + 4096);                         \
    gload16(ag0 + (kt) * 32 + 131072, asb + 8192);                         \
    gload16(ag0 + (kt) * 32 + 196608, asb + 12288);                        \
    gload16(bg0 + (kt) * 32,          bsb);                                \
    gload16(bg0 + (kt) * 32 + 65536,  bsb + 4096);                         \
  }

  // prologue: stage tile 0 into slot 0
  STAGE_G(0, 0)
  asm volatile("s_waitcnt vmcnt(0)" ::: "memory");
  __builtin_amdgcn_s_barrier();
  __builtin_amdgcn_sched_barrier(0);

#pragma unroll 1
  for (int kt = 0; kt < 32; kt++) {
    const int cur = kt & 1;
    if (kt < 31) STAGE_G(kt + 1, cur ^ 1)   // overlaps the MFMA below
    const char* ab = (const char*)As + cur * 16384;
    const char* bb = (const char*)Bs + cur * 8192;
    bf16x8 bfr[4];
#pragma unroll
    for (int n = 0; n < 4; n++) bfr[n] = *(const bf16x8*)(bb + boff[n]);
#pragma unroll
    for (int m = 0; m < 8; m++) {
      bf16x8 af = *(const bf16x8*)(ab + aoff[m]);
#pragma unroll
      for (int n = 0; n < 4; n++)
        acc[m][n] = mfma16(af, bfr[n], acc[m][n]);
    }
    if (kt < 31) {
      asm volatile("s_waitcnt vmcnt(0)" ::: "memory");  // tile kt+1 landed
      __builtin_amdgcn_s_barrier();
      __builtin_amdgcn_sched_barrier(0);
    }
  }
#undef STAGE_G

  if (mode == 0) {
    unsigned short* C = (unsigned short*)outp;
#pragma unroll
    for (int m = 0; m < 8; m++) {
      int r = brow + wr + m * 16 + 4 * lk;
#pragma unroll
      for (int n = 0; n < 4; n++) {
        int c = bcol + wc + n * 16 + lrow;
        unsigned short* p = C + ((r >> 10) * 16 + (c >> 6)) * 65536 + (r & 1023) * 64 + (c & 63);
#pragma unroll
        for (int j = 0; j < 4; j++) p[j * 64] = f2bf(acc[m][n][j] * oscale);
      }
    }
  } else if (mode == 2) {
    unsigned short* C = (unsigned short*)outp;
#pragma unroll
    for (int m = 0; m < 8; m++) {
      int r = brow + wr + m * 16 + 4 * lk;
#pragma unroll
      for (int n = 0; n < 4; n++) {
        int c = bcol + wc + n * 16 + lrow;
        u16x4 o;
#pragma unroll
        for (int j = 0; j < 4; j++) o[j] = f2bf(acc[m][n][j]);
        *(u16x4*)(C + ((r >> 10) * 16 + (c >> 6)) * 65536 + (c & 63) * 1024 + (r & 1023)) = o;
      }
    }
  } else {
    float* C = (float*)outp;
#pragma unroll
    for (int m = 0; m < 8; m++) {
      int r = brow + wr + m * 16 + 4 * lk;
#pragma unroll
      for (int n = 0; n < 4; n++) {
        int c = bcol + wc + n * 16 + lrow;
#pragma unroll
        for (int j = 0; j < 4; j++) C[(r + j) * 1024 + c] = acc[m][n][j];
      }
    }
  }
}

__global__ __launch_bounds__(256, 3) void k_gemm_qkv(const unsigned short* __restrict__ Xb,
                                                     const unsigned short* __restrict__ Zb,
                                                     const unsigned short* __restrict__ Wqkv,
                                                     const float* __restrict__ bq,
                                                     const float* __restrict__ bk,
                                                     const float* __restrict__ bv,
                                                     unsigned short* __restrict__ Qp,
                                                     unsigned short* __restrict__ Kp,
                                                     unsigned short* __restrict__ Vtp) {
  __shared__ unsigned short As[16384];  // 2 slots x 16 KB = 32 KB
  __shared__ unsigned short Bs[8192];   // 2 slots x 8 KB  = 16 KB -> 48 KB total
  const int brow = blockIdx.x * 256;
  const int cg = blockIdx.y;
  const int seg = cg >> 3;
  const int bcol = (cg & 7) * 128;
  const unsigned short* A = (seg == 0) ? Xb : Zb;
  const unsigned short* Bt = Wqkv + (size_t)seg * 1048576;
  const float* bias = (seg == 0) ? bq : (seg == 1 ? bk : bv);
  void* outp = (seg == 0) ? (void*)Qp : (seg == 1 ? (void*)Kp : (void*)Vtp);
  const int mode = (seg == 2) ? 2 : 0;
  const float oscale = (seg == 0) ? QSCALE_F : 1.0f;
  gemm_body(A, Bt, bias, outp, mode, oscale, brow, bcol, As, Bs);
}

__global__ __launch_bounds__(256, 3) void k_gemm(const unsigned short* __restrict__ A,
                                                 const unsigned short* __restrict__ Bt,
                                                 const float* __restrict__ bias,
                                                 void* __restrict__ outp,
                                                 int mode, float oscale) {
  __shared__ unsigned short As[16384];
  __shared__ unsigned short Bs[8192];
  gemm_body(A, Bt, bias, outp, mode, oscale, blockIdx.x * 256, blockIdx.y * 128, As, Bs);
}

// ---------------- flash attention (r18 verbatim) ----------------
// grid (128, 4): bh = blockIdx.x, pp = blockIdx.y -> id%8 = bh%8: XCD-local K/V (4 MB/XCD).
__global__ __launch_bounds__(256, 2) void k_attn(const unsigned short* __restrict__ Qh,
                                                 const unsigned short* __restrict__ Kh,
                                                 const unsigned short* __restrict__ Vth,
                                                 unsigned short* __restrict__ Y) {
  __shared__ unsigned short Ks[16384];  // 2 x (128 z x 64 d) swizzled, 32 KB
  __shared__ unsigned short Vs[16384];  // 2 x (64 e x 128 z) swizzled, 32 KB
  __shared__ unsigned short Ps[8192];   // 4 waves x (32 q x 64 z) swizzled, 16 KB

  const int tid = threadIdx.x, l = tid & 63, w = tid >> 6;
  const int lrow = l & 15, lk = l >> 4;
  const int bh = blockIdx.x;
  const int pp = blockIdx.y;

  const unsigned short* Qb = Qh + bh * 65536;
  const unsigned short* Kb = Kh + bh * 65536;
  const unsigned short* Vb = Vth + bh * 65536;

  bf16x8 ones;
#pragma unroll
  for (int j = 0; j < 8; j++) ones[j] = (__bf16)1.0f;

  const int krl = l >> 3;
  const int kgp = l & 7;
  const unsigned short* kgsrc = Kb + (w * 32 + krl) * 64 + ((kgp ^ krl) * 8);
  const int vrl = l >> 4;
  const int vgp = l & 15;
  const int vr0 = w * 16 + 0 * 4 + vrl;
  const int vr1 = w * 16 + 1 * 4 + vrl;
  const int vr2 = w * 16 + 2 * 4 + vrl;
  const int vr3 = w * 16 + 3 * 4 + vrl;
  const int voff0 = vr0 * 1024 + ((vgp ^ (vr0 & 15)) * 8);
  const int voff1 = vr1 * 1024 + ((vgp ^ (vr1 & 15)) * 8);
  const int voff2 = vr2 * 1024 + ((vgp ^ (vr2 & 15)) * 8);
  const int voff3 = vr3 * 1024 + ((vgp ^ (vr3 & 15)) * 8);

  char* pw = (char*)Ps + w * 4096;

  const int b = bh >> 4, h = bh & 15;

#pragma unroll 1
  for (int hp = 0; hp < 2; hp++) {
    const int qi = hp == 0 ? (7 - pp) : pp;
    const int qw = qi * 128 + w * 32;
    const int qmax = qw + 31;

    bf16x8 qf[2][2];
#pragma unroll
    for (int qn = 0; qn < 2; qn++) {
      const unsigned short* qp = Qb + (qw + qn * 16 + lrow) * 64 + lk * 8;
      qf[qn][0] = *(const bf16x8*)qp;
      qf[qn][1] = *(const bf16x8*)(qp + 32);
    }

    float mm[2];
    f32x4 lsum[2], yacc[2][4];
#pragma unroll
    for (int qn = 0; qn < 2; qn++) {
      mm[qn] = MASKNEG;
      lsum[qn] = (f32x4){0.f, 0.f, 0.f, 0.f};
#pragma unroll
      for (int ef = 0; ef < 4; ef++) yacc[qn][ef] = (f32x4){0.f, 0.f, 0.f, 0.f};
    }

    const int nt = qi + 1;

    {
      char* kb = (char*)Ks + w * 4096;
      char* vb2 = (char*)Vs + w * 4096;
      gload16(kgsrc + 0,    kb);
      gload16(kgsrc + 512,  kb + 1024);
      gload16(kgsrc + 1024, kb + 2048);
      gload16(kgsrc + 1536, kb + 3072);
      gload16(Vb + voff0, vb2);
      gload16(Vb + voff1, vb2 + 1024);
      gload16(Vb + voff2, vb2 + 2048);
      gload16(Vb + voff3, vb2 + 3072);
    }
    __syncthreads();

#pragma unroll 1
    for (int t = 0; t < nt; t++) {
      const int z0 = t * 128;
      const int cur = t & 1;
      if (t < nt - 1) {
        const int zn = (t + 1) * 128;
        char* kb = (char*)Ks + (cur ^ 1) * 16384 + w * 4096;
        char* vb2 = (char*)Vs + (cur ^ 1) * 16384 + w * 4096;
        const unsigned short* kgt = kgsrc + zn * 64;
        gload16(kgt + 0,    kb);
        gload16(kgt + 512,  kb + 1024);
        gload16(kgt + 1024, kb + 2048);
        gload16(kgt + 1536, kb + 3072);
        gload16(Vb + voff0 + zn, vb2);
        gload16(Vb + voff1 + zn, vb2 + 1024);
        gload16(Vb + voff2 + zn, vb2 + 2048);
        gload16(Vb + voff3 + zn, vb2 + 3072);
      }

      if (z0 <= qmax) {
        const char* kbase = (const char*)Ks + cur * 16384;
        const char* vbase = (const char*)Vs + cur * 16384;

        // S^T: lane holds S[z = z0 + zf*16 + 4*lk + j][q = qw + qn*16 + lrow]
        f32x4 s[2][8];
#pragma unroll
        for (int qn = 0; qn < 2; qn++)
#pragma unroll
          for (int zf = 0; zf < 8; zf++) s[qn][zf] = (f32x4){0.f, 0.f, 0.f, 0.f};
#pragma unroll
        for (int zf = 0; zf < 8; zf++) {
          int zr = zf * 16 + lrow;
#pragma unroll
          for (int kf = 0; kf < 2; kf++) {
            bf16x8 kfr = *(const bf16x8*)(kbase + zr * 128 + (((kf * 4 + lk) ^ (zr & 7)) << 4));
            s[0][zf] = mfma16(kfr, qf[0][kf], s[0][zf]);
            s[1][zf] = mfma16(kfr, qf[1][kf], s[1][zf]);
          }
        }

        if (z0 + 127 > qw) {   // diagonal overlap: mask z > q
#pragma unroll
          for (int qn = 0; qn < 2; qn++) {
            int qg = qw + qn * 16 + lrow;
#pragma unroll
            for (int zf = 0; zf < 8; zf++) {
              int zb = z0 + zf * 16 + 4 * lk;
#pragma unroll
              for (int j = 0; j < 4; j++)
                if (zb + j > qg) s[qn][zf][j] = MASKNEG;
            }
          }
        }

        // in-lane softmax: 31 fmax + 2 shfls; defer-max THR=8 (log2 domain)
#pragma unroll
        for (int qn = 0; qn < 2; qn++) {
          f32x4 r4 = s[qn][0];
#pragma unroll
          for (int zf = 1; zf < 8; zf++)
#pragma unroll
            for (int j = 0; j < 4; j++) r4[j] = fmaxf(r4[j], s[qn][zf][j]);
          float rm = fmaxf(fmaxf(r4[0], r4[1]), fmaxf(r4[2], r4[3]));
          rm = fmaxf(rm, __shfl_xor(rm, 16));
          rm = fmaxf(rm, __shfl_xor(rm, 32));

          if (__any(rm > mm[qn] + 8.f)) {
            float mn = fmaxf(mm[qn], rm);
            float a = __builtin_amdgcn_exp2f(mm[qn] - mn);  // <= 0 arg
            mm[qn] = mn;
            f32x4 av;
#pragma unroll
            for (int j = 0; j < 4; j++)
              av[j] = __shfl(a, (l & 48) | (lk * 4 + j));
            lsum[qn] *= av;
#pragma unroll
            for (int ef = 0; ef < 4; ef++) yacc[qn][ef] *= av;
          }
          float mk = mm[qn];
#pragma unroll
          for (int zf = 0; zf < 8; zf++)
#pragma unroll
            for (int j = 0; j < 4; j++)
              s[qn][zf][j] = __builtin_amdgcn_exp2f(s[qn][zf][j] - mk);  // <= 2^8
        }

        // PV in two 64-z halves
#pragma unroll
        for (int hf = 0; hf < 2; hf++) {
          if (z0 + hf * 64 <= qmax) {
            // P^T -> P[q][z] rows in LDS (vectorized u16x4; native bf16 casts)
#pragma unroll
            for (int qn = 0; qn < 2; qn++) {
              int q = qn * 16 + lrow;
              char* rowp = pw + q * 128;
#pragma unroll
              for (int zf2 = 0; zf2 < 4; zf2++) {
                int zfg = hf * 4 + zf2;
                u16x4 o;
#pragma unroll
                for (int j = 0; j < 4; j++) o[j] = f2bf_hw(s[qn][zfg][j]);
                int g = zf2 * 2 + (lk >> 1);
                *(u16x4*)(rowp + ((g ^ (q & 7)) << 4) + (lk & 1) * 8) = o;
              }
            }

            asm volatile("s_waitcnt lgkmcnt(0)" ::: "memory");
            __builtin_amdgcn_sched_barrier(0);

            bf16x8 pf[2][2];
#pragma unroll
            for (int qn = 0; qn < 2; qn++)
#pragma unroll
              for (int kf = 0; kf < 2; kf++)
                pf[qn][kf] = *(const bf16x8*)(pw + (qn * 16 + lrow) * 128 + (((kf * 4 + lk) ^ (lrow & 7)) << 4));

#pragma unroll
            for (int qn = 0; qn < 2; qn++)
#pragma unroll
              for (int kf = 0; kf < 2; kf++)
                lsum[qn] = mfma16(pf[qn][kf], ones, lsum[qn]);

#pragma unroll
            for (int ef = 0; ef < 4; ef++) {
              int er = ef * 16 + lrow;
#pragma unroll
              for (int kf = 0; kf < 2; kf++) {
                int g = hf * 8 + kf * 4 + lk;
                bf16x8 vf = *(const bf16x8*)(vbase + er * 256 + ((g ^ (er & 15)) << 4));
                yacc[0][ef] = mfma16(pf[0][kf], vf, yacc[0][ef]);
                yacc[1][ef] = mfma16(pf[1][kf], vf, yacc[1][ef]);
              }
            }
          }
        }
      }

      __syncthreads();
    }

    // epilogue (native bf16 casts): q = qw + qn*16 + lk*4 + j, e = ef*16 + lrow
#pragma unroll
    for (int qn = 0; qn < 2; qn++) {
      f32x4 rinv;
#pragma unroll
      for (int j = 0; j < 4; j++) rinv[j] = 1.0f / lsum[qn][j];
#pragma unroll
      for (int ef = 0; ef < 4; ef++) {
        int col = h * 64 + ef * 16 + lrow;
#pragma unroll
        for (int j = 0; j < 4; j++) {
          int x = qw + qn * 16 + lk * 4 + j;
          Y[(b * 1024 + x) * 1024 + col] = f2bf_hw(yacc[qn][ef][j] * rinv[j]);
        }
      }
    }
  }
}

// ---------------- launch ----------------
extern "C" void kernel_launch(void* const* d_in, const int* in_sizes, int n_in,
                              void* d_out, int out_size, void* d_ws, size_t ws_size,
                              hipStream_t stream) {
  const float* x  = (const float*)d_in[0];
  const float* z  = (const float*)d_in[1];
  const float* Wq = (const float*)d_in[2];
  const float* bq = (const float*)d_in[3];
  const float* Wk = (const float*)d_in[4];
  const float* bk = (const float*)d_in[5];
  const float* Wv = (const float*)d_in[6];
  const float* bv = (const float*)d_in[7];
  const float* Wp = (const float*)d_in[8];
  const float* bp = (const float*)d_in[9];
  (void)in_sizes; (void)n_in; (void)out_size; (void)ws_size;

  char* ws = (char*)d_ws;
  unsigned short* Xb  = (unsigned short*)(ws + 0);
  unsigned short* Zb  = (unsigned short*)(ws + 16777216);
  unsigned short* Wqt = (unsigned short*)(ws + 33554432);  // Wqt/Wkt/Wvt contiguous = Wqkv
  unsigned short* Wkt = (unsigned short*)(ws + 35651584);
  unsigned short* Wvt = (unsigned short*)(ws + 37748736);
  unsigned short* Wpt = (unsigned short*)(ws + 39845888);
  unsigned short* Qp  = (unsigned short*)(ws + 41943040);
  unsigned short* Kp  = (unsigned short*)(ws + 58720256);
  unsigned short* Vtp = (unsigned short*)(ws + 75497472);

  k_cvt2<<<dim3(2048), dim3(256), 0, stream>>>(x, z, Xb);
  k_pack<<<dim3(16, 16, 4), dim3(256), 0, stream>>>(Wq, Wk, Wv, Wp, Wqt, Wkt, Wvt, Wpt);

  k_gemm_qkv<<<dim3(32, 24), dim3(256), 0, stream>>>(Xb, Zb, Wqt, bq, bk, bv, Qp, Kp, Vtp);

  k_attn<<<dim3(128, 4), dim3(256), 0, stream>>>(Qp, Kp, Vtp, Xb /*Y*/);

  k_gemm<<<dim3(32, 8), dim3(256), 0, stream>>>(Xb, Wpt, bp, d_out, 3, 1.0f);
}

// Round 20
// 142.955 us; speedup vs baseline: 1.0712x; 1.0236x over previous
//
#include <hip/hip_runtime.h>
#include <stdint.h>

// Pipeline: k_prep (cvt x,z -> bf16 AND pack weights, one dispatch, independent work
// co-scheduled); fused QKV GEMM (256x128 tile, 2-slot dbuf, 48KB LDS, 3 blocks/CU);
// flash attention (staged KVBLK=128, swapped QK^T, in-lane softmax, defer-max,
// XCD-local grid, native bf16 casts); output GEMM -> f32.
// v_cvt_pk_bf16_f32 INLINE ASM BANNED (NaN culprit; compiler-emitted converts OK).
// Direct-from-global K/V BANNED (r15). Phased GEMM schedules closed out (r13/r17).
// B=8 TX=TZ=1024 DX=DZ=1024 DATT=DMID=64 H=16 DOUT=1024.

typedef float    f32x4  __attribute__((ext_vector_type(4)));
typedef __bf16   bf16x8 __attribute__((ext_vector_type(8)));
typedef unsigned short u16x4 __attribute__((ext_vector_type(4)));
typedef unsigned short u16x8 __attribute__((ext_vector_type(8)));

#define MASKNEG (-3.0e38f)
#define QSCALE_F (0.125f * 1.4426950408889634f)

__device__ __forceinline__ unsigned short f2bf(float f) {
  unsigned int u = __float_as_uint(f);
  u += 0x7fffu + ((u >> 16) & 1u);   // RNE (software)
  return (unsigned short)(u >> 16);
}

// native hardware convert (compiler may fold pairs into v_cvt_pk_bf16_f32)
__device__ __forceinline__ unsigned short f2bf_hw(float f) {
  __bf16 h = (__bf16)f;
  return *(unsigned short*)&h;
}

__device__ __forceinline__ void gload16(const void* g, void* s) {
  const __attribute__((address_space(1))) unsigned int* gp =
      (const __attribute__((address_space(1))) unsigned int*)(uintptr_t)g;
  __attribute__((address_space(3))) unsigned int* lp =
      (__attribute__((address_space(3))) unsigned int*)(unsigned int)(uintptr_t)s;
  __builtin_amdgcn_global_load_lds(gp, lp, 16, 0, 0);
}

__device__ __forceinline__ f32x4 mfma16(bf16x8 a, bf16x8 b, f32x4 c) {
  return __builtin_amdgcn_mfma_f32_16x16x32_bf16(a, b, c, 0, 0, 0);
}

// ---------------- fused prep: cvt (bid<2048) + weight pack (bid>=2048) ----------------
// cvt and pack are independent (disjoint outputs); one dispatch lets them co-schedule.
__global__ __launch_bounds__(256) void k_prep(const float* __restrict__ x,
                                              const float* __restrict__ z,
                                              unsigned short* __restrict__ out,
                                              const float* __restrict__ Wq,
                                              const float* __restrict__ Wk,
                                              const float* __restrict__ Wv,
                                              const float* __restrict__ Wp,
                                              unsigned short* __restrict__ Oq,
                                              unsigned short* __restrict__ Ok,
                                              unsigned short* __restrict__ Ov,
                                              unsigned short* __restrict__ Op) {
  __shared__ float tile[64][65];
  const int bid = blockIdx.x;
  const int t = threadIdx.x;

  if (bid < 2048) {
    // cvt path (r12-validated body; grid-stride over 2048 blocks)
    int i = bid * 256 + t;
    const int stride = 2048 * 256;
    for (; i < 2097152; i += stride) {
      const float* in = (i < 1048576) ? (x + (size_t)i * 8) : (z + (size_t)(i - 1048576) * 8);
      const f32x4* p = (const f32x4*)in;
      f32x4 a = p[0], b = p[1];
      u16x8 o;
      o[0] = f2bf(a[0]); o[1] = f2bf(a[1]); o[2] = f2bf(a[2]); o[3] = f2bf(a[3]);
      o[4] = f2bf(b[0]); o[5] = f2bf(b[1]); o[6] = f2bf(b[2]); o[7] = f2bf(b[3]);
      *(u16x8*)(out + (size_t)i * 8) = o;
    }
    return;
  }

  // pack path (r12-validated body; (16,16,4) linearized: pid = bid-2048)
  const int pid = bid - 2048;
  const int zid = pid >> 8;            // 0..3
  const int bx = (pid >> 4) & 15;      // 0..15
  const int by = pid & 15;             // 0..15

  if (zid < 3) {
    const float* W = zid == 0 ? Wq : (zid == 1 ? Wk : Wv);
    unsigned short* O = zid == 0 ? Oq : (zid == 1 ? Ok : Ov);
    const int h = bx, d0 = by * 64;
    const int ee = t & 63, r0 = t >> 6;
#pragma unroll
    for (int dd = r0; dd < 64; dd += 4)
      tile[dd][ee] = W[(h * 1024 + d0 + dd) * 64 + ee];
    __syncthreads();
    const int d = t & 63, e0 = t >> 6;
#pragma unroll
    for (int e = e0; e < 64; e += 4)
      O[(h * 64 + e) * 1024 + d0 + d] = f2bf(tile[d][e]);
  } else {
    const int k0 = bx * 64, n0 = by * 64;
    const int nn = t & 63, r0 = t >> 6;
#pragma unroll
    for (int kk = r0; kk < 64; kk += 4)
      tile[kk][nn] = Wp[(k0 + kk) * 1024 + n0 + nn];
    __syncthreads();
    const int kk = t & 63, e0 = t >> 6;
#pragma unroll
    for (int n2 = e0; n2 < 64; n2 += 4)
      Op[(n0 + n2) * 1024 + k0 + kk] = f2bf(tile[kk][n2]);
  }
}

// ---------------- GEMM body: C[256x128 tile] = A * Bt^T + bias (r19 verbatim) ----------------
// 2-slot double buffer (48 KB LDS -> 3 blocks/CU): stage kt+1 at top into slot^1,
// compute slot, vmcnt(0)+barrier at bottom. Cross-block TLP hides the drain.
__device__ __forceinline__ void gemm_body(const unsigned short* __restrict__ A,
                                          const unsigned short* __restrict__ Bt,
                                          const float* __restrict__ bias,
                                          void* __restrict__ outp,
                                          int mode, float oscale,
                                          int brow, int bcol,
                                          unsigned short* As, unsigned short* Bs) {
  const int tid = threadIdx.x;
  const int l = tid & 63, w = tid >> 6;
  const int lrow = l & 15, lk = l >> 4;
  const int wr = (w >> 1) * 128, wc = (w & 1) * 64;

  const int arow = tid >> 2;
  const int asrc = ((tid & 3) ^ ((arow >> 1) & 3)) * 8;
  const unsigned short* ag0 = A + (size_t)(brow + arow) * 1024 + asrc;
  const unsigned short* bg0 = Bt + (size_t)(bcol + arow) * 1024 + asrc;

  int aoff[8], boff[4];
#pragma unroll
  for (int m = 0; m < 8; m++) {
    int row = wr + m * 16 + lrow;
    aoff[m] = row * 64 + ((lk ^ ((row >> 1) & 3)) << 4);
  }
#pragma unroll
  for (int n = 0; n < 4; n++) {
    int col = wc + n * 16 + lrow;
    boff[n] = col * 64 + ((lk ^ ((col >> 1) & 3)) << 4);
  }

  f32x4 acc[8][4];
#pragma unroll
  for (int n = 0; n < 4; n++) {
    float bv = bias[bcol + wc + n * 16 + lrow];
#pragma unroll
    for (int m = 0; m < 8; m++) acc[m][n] = (f32x4){bv, bv, bv, bv};
  }

#define STAGE_G(kt, slot)                                                  \
  {                                                                        \
    char* asb = (char*)As + (slot) * 16384 + w * 1024;                     \
    char* bsb = (char*)Bs + (slot) * 8192 + w * 1024;                      \
    gload16(ag0 + (kt) * 32,          asb);                                \
    gload16(ag0 + (kt) * 32 + 65536,  asb + 4096);                         \
    gload16(ag0 + (kt) * 32 + 131072, asb + 8192);                         \
    gload16(ag0 + (kt) * 32 + 196608, asb + 12288);                        \
    gload16(bg0 + (kt) * 32,          bsb);                                \
    gload16(bg0 + (kt) * 32 + 65536,  bsb + 4096);                         \
  }

  STAGE_G(0, 0)
  asm volatile("s_waitcnt vmcnt(0)" ::: "memory");
  __builtin_amdgcn_s_barrier();
  __builtin_amdgcn_sched_barrier(0);

#pragma unroll 1
  for (int kt = 0; kt < 32; kt++) {
    const int cur = kt & 1;
    if (kt < 31) STAGE_G(kt + 1, cur ^ 1)
    const char* ab = (const char*)As + cur * 16384;
    const char* bb = (const char*)Bs + cur * 8192;
    bf16x8 bfr[4];
#pragma unroll
    for (int n = 0; n < 4; n++) bfr[n] = *(const bf16x8*)(bb + boff[n]);
#pragma unroll
    for (int m = 0; m < 8; m++) {
      bf16x8 af = *(const bf16x8*)(ab + aoff[m]);
#pragma unroll
      for (int n = 0; n < 4; n++)
        acc[m][n] = mfma16(af, bfr[n], acc[m][n]);
    }
    if (kt < 31) {
      asm volatile("s_waitcnt vmcnt(0)" ::: "memory");
      __builtin_amdgcn_s_barrier();
      __builtin_amdgcn_sched_barrier(0);
    }
  }
#undef STAGE_G

  if (mode == 0) {
    unsigned short* C = (unsigned short*)outp;
#pragma unroll
    for (int m = 0; m < 8; m++) {
      int r = brow + wr + m * 16 + 4 * lk;
#pragma unroll
      for (int n = 0; n < 4; n++) {
        int c = bcol + wc + n * 16 + lrow;
        unsigned short* p = C + ((r >> 10) * 16 + (c >> 6)) * 65536 + (r & 1023) * 64 + (c & 63);
#pragma unroll
        for (int j = 0; j < 4; j++) p[j * 64] = f2bf(acc[m][n][j] * oscale);
      }
    }
  } else if (mode == 2) {
    unsigned short* C = (unsigned short*)outp;
#pragma unroll
    for (int m = 0; m < 8; m++) {
      int r = brow + wr + m * 16 + 4 * lk;
#pragma unroll
      for (int n = 0; n < 4; n++) {
        int c = bcol + wc + n * 16 + lrow;
        u16x4 o;
#pragma unroll
        for (int j = 0; j < 4; j++) o[j] = f2bf(acc[m][n][j]);
        *(u16x4*)(C + ((r >> 10) * 16 + (c >> 6)) * 65536 + (c & 63) * 1024 + (r & 1023)) = o;
      }
    }
  } else {
    float* C = (float*)outp;
#pragma unroll
    for (int m = 0; m < 8; m++) {
      int r = brow + wr + m * 16 + 4 * lk;
#pragma unroll
      for (int n = 0; n < 4; n++) {
        int c = bcol + wc + n * 16 + lrow;
#pragma unroll
        for (int j = 0; j < 4; j++) C[(r + j) * 1024 + c] = acc[m][n][j];
      }
    }
  }
}

__global__ __launch_bounds__(256, 3) void k_gemm_qkv(const unsigned short* __restrict__ Xb,
                                                     const unsigned short* __restrict__ Zb,
                                                     const unsigned short* __restrict__ Wqkv,
                                                     const float* __restrict__ bq,
                                                     const float* __restrict__ bk,
                                                     const float* __restrict__ bv,
                                                     unsigned short* __restrict__ Qp,
                                                     unsigned short* __restrict__ Kp,
                                                     unsigned short* __restrict__ Vtp) {
  __shared__ unsigned short As[16384];  // 2 slots x 16 KB = 32 KB
  __shared__ unsigned short Bs[8192];   // 2 slots x 8 KB  = 16 KB -> 48 KB total
  const int brow = blockIdx.x * 256;
  const int cg = blockIdx.y;
  const int seg = cg >> 3;
  const int bcol = (cg & 7) * 128;
  const unsigned short* A = (seg == 0) ? Xb : Zb;
  const unsigned short* Bt = Wqkv + (size_t)seg * 1048576;
  const float* bias = (seg == 0) ? bq : (seg == 1 ? bk : bv);
  void* outp = (seg == 0) ? (void*)Qp : (seg == 1 ? (void*)Kp : (void*)Vtp);
  const int mode = (seg == 2) ? 2 : 0;
  const float oscale = (seg == 0) ? QSCALE_F : 1.0f;
  gemm_body(A, Bt, bias, outp, mode, oscale, brow, bcol, As, Bs);
}

__global__ __launch_bounds__(256, 3) void k_gemm(const unsigned short* __restrict__ A,
                                                 const unsigned short* __restrict__ Bt,
                                                 const float* __restrict__ bias,
                                                 void* __restrict__ outp,
                                                 int mode, float oscale) {
  __shared__ unsigned short As[16384];
  __shared__ unsigned short Bs[8192];
  gemm_body(A, Bt, bias, outp, mode, oscale, blockIdx.x * 256, blockIdx.y * 128, As, Bs);
}

// ---------------- flash attention (r18/r19 verbatim) ----------------
// grid (128, 4): bh = blockIdx.x, pp = blockIdx.y -> id%8 = bh%8: XCD-local K/V (4 MB/XCD).
__global__ __launch_bounds__(256, 2) void k_attn(const unsigned short* __restrict__ Qh,
                                                 const unsigned short* __restrict__ Kh,
                                                 const unsigned short* __restrict__ Vth,
                                                 unsigned short* __restrict__ Y) {
  __shared__ unsigned short Ks[16384];  // 2 x (128 z x 64 d) swizzled, 32 KB
  __shared__ unsigned short Vs[16384];  // 2 x (64 e x 128 z) swizzled, 32 KB
  __shared__ unsigned short Ps[8192];   // 4 waves x (32 q x 64 z) swizzled, 16 KB

  const int tid = threadIdx.x, l = tid & 63, w = tid >> 6;
  const int lrow = l & 15, lk = l >> 4;
  const int bh = blockIdx.x;
  const int pp = blockIdx.y;

  const unsigned short* Qb = Qh + bh * 65536;
  const unsigned short* Kb = Kh + bh * 65536;
  const unsigned short* Vb = Vth + bh * 65536;

  bf16x8 ones;
#pragma unroll
  for (int j = 0; j < 8; j++) ones[j] = (__bf16)1.0f;

  const int krl = l >> 3;
  const int kgp = l & 7;
  const unsigned short* kgsrc = Kb + (w * 32 + krl) * 64 + ((kgp ^ krl) * 8);
  const int vrl = l >> 4;
  const int vgp = l & 15;
  const int vr0 = w * 16 + 0 * 4 + vrl;
  const int vr1 = w * 16 + 1 * 4 + vrl;
  const int vr2 = w * 16 + 2 * 4 + vrl;
  const int vr3 = w * 16 + 3 * 4 + vrl;
  const int voff0 = vr0 * 1024 + ((vgp ^ (vr0 & 15)) * 8);
  const int voff1 = vr1 * 1024 + ((vgp ^ (vr1 & 15)) * 8);
  const int voff2 = vr2 * 1024 + ((vgp ^ (vr2 & 15)) * 8);
  const int voff3 = vr3 * 1024 + ((vgp ^ (vr3 & 15)) * 8);

  char* pw = (char*)Ps + w * 4096;

  const int b = bh >> 4, h = bh & 15;

#pragma unroll 1
  for (int hp = 0; hp < 2; hp++) {
    const int qi = hp == 0 ? (7 - pp) : pp;
    const int qw = qi * 128 + w * 32;
    const int qmax = qw + 31;

    bf16x8 qf[2][2];
#pragma unroll
    for (int qn = 0; qn < 2; qn++) {
      const unsigned short* qp = Qb + (qw + qn * 16 + lrow) * 64 + lk * 8;
      qf[qn][0] = *(const bf16x8*)qp;
      qf[qn][1] = *(const bf16x8*)(qp + 32);
    }

    float mm[2];
    f32x4 lsum[2], yacc[2][4];
#pragma unroll
    for (int qn = 0; qn < 2; qn++) {
      mm[qn] = MASKNEG;
      lsum[qn] = (f32x4){0.f, 0.f, 0.f, 0.f};
#pragma unroll
      for (int ef = 0; ef < 4; ef++) yacc[qn][ef] = (f32x4){0.f, 0.f, 0.f, 0.f};
    }

    const int nt = qi + 1;

    {
      char* kb = (char*)Ks + w * 4096;
      char* vb2 = (char*)Vs + w * 4096;
      gload16(kgsrc + 0,    kb);
      gload16(kgsrc + 512,  kb + 1024);
      gload16(kgsrc + 1024, kb + 2048);
      gload16(kgsrc + 1536, kb + 3072);
      gload16(Vb + voff0, vb2);
      gload16(Vb + voff1, vb2 + 1024);
      gload16(Vb + voff2, vb2 + 2048);
      gload16(Vb + voff3, vb2 + 3072);
    }
    __syncthreads();

#pragma unroll 1
    for (int t = 0; t < nt; t++) {
      const int z0 = t * 128;
      const int cur = t & 1;
      if (t < nt - 1) {
        const int zn = (t + 1) * 128;
        char* kb = (char*)Ks + (cur ^ 1) * 16384 + w * 4096;
        char* vb2 = (char*)Vs + (cur ^ 1) * 16384 + w * 4096;
        const unsigned short* kgt = kgsrc + zn * 64;
        gload16(kgt + 0,    kb);
        gload16(kgt + 512,  kb + 1024);
        gload16(kgt + 1024, kb + 2048);
        gload16(kgt + 1536, kb + 3072);
        gload16(Vb + voff0 + zn, vb2);
        gload16(Vb + voff1 + zn, vb2 + 1024);
        gload16(Vb + voff2 + zn, vb2 + 2048);
        gload16(Vb + voff3 + zn, vb2 + 3072);
      }

      if (z0 <= qmax) {
        const char* kbase = (const char*)Ks + cur * 16384;
        const char* vbase = (const char*)Vs + cur * 16384;

        // S^T: lane holds S[z = z0 + zf*16 + 4*lk + j][q = qw + qn*16 + lrow]
        f32x4 s[2][8];
#pragma unroll
        for (int qn = 0; qn < 2; qn++)
#pragma unroll
          for (int zf = 0; zf < 8; zf++) s[qn][zf] = (f32x4){0.f, 0.f, 0.f, 0.f};
#pragma unroll
        for (int zf = 0; zf < 8; zf++) {
          int zr = zf * 16 + lrow;
#pragma unroll
          for (int kf = 0; kf < 2; kf++) {
            bf16x8 kfr = *(const bf16x8*)(kbase + zr * 128 + (((kf * 4 + lk) ^ (zr & 7)) << 4));
            s[0][zf] = mfma16(kfr, qf[0][kf], s[0][zf]);
            s[1][zf] = mfma16(kfr, qf[1][kf], s[1][zf]);
          }
        }

        if (z0 + 127 > qw) {   // diagonal overlap: mask z > q
#pragma unroll
          for (int qn = 0; qn < 2; qn++) {
            int qg = qw + qn * 16 + lrow;
#pragma unroll
            for (int zf = 0; zf < 8; zf++) {
              int zb = z0 + zf * 16 + 4 * lk;
#pragma unroll
              for (int j = 0; j < 4; j++)
                if (zb + j > qg) s[qn][zf][j] = MASKNEG;
            }
          }
        }

        // in-lane softmax: 31 fmax + 2 shfls; defer-max THR=8 (log2 domain)
#pragma unroll
        for (int qn = 0; qn < 2; qn++) {
          f32x4 r4 = s[qn][0];
#pragma unroll
          for (int zf = 1; zf < 8; zf++)
#pragma unroll
            for (int j = 0; j < 4; j++) r4[j] = fmaxf(r4[j], s[qn][zf][j]);
          float rm = fmaxf(fmaxf(r4[0], r4[1]), fmaxf(r4[2], r4[3]));
          rm = fmaxf(rm, __shfl_xor(rm, 16));
          rm = fmaxf(rm, __shfl_xor(rm, 32));

          if (__any(rm > mm[qn] + 8.f)) {
            float mn = fmaxf(mm[qn], rm);
            float a = __builtin_amdgcn_exp2f(mm[qn] - mn);  // <= 0 arg
            mm[qn] = mn;
            f32x4 av;
#pragma unroll
            for (int j = 0; j < 4; j++)
              av[j] = __shfl(a, (l & 48) | (lk * 4 + j));
            lsum[qn] *= av;
#pragma unroll
            for (int ef = 0; ef < 4; ef++) yacc[qn][ef] *= av;
          }
          float mk = mm[qn];
#pragma unroll
          for (int zf = 0; zf < 8; zf++)
#pragma unroll
            for (int j = 0; j < 4; j++)
              s[qn][zf][j] = __builtin_amdgcn_exp2f(s[qn][zf][j] - mk);  // <= 2^8
        }

        // PV in two 64-z halves
#pragma unroll
        for (int hf = 0; hf < 2; hf++) {
          if (z0 + hf * 64 <= qmax) {
            // P^T -> P[q][z] rows in LDS (vectorized u16x4; native bf16 casts)
#pragma unroll
            for (int qn = 0; qn < 2; qn++) {
              int q = qn * 16 + lrow;
              char* rowp = pw + q * 128;
#pragma unroll
              for (int zf2 = 0; zf2 < 4; zf2++) {
                int zfg = hf * 4 + zf2;
                u16x4 o;
#pragma unroll
                for (int j = 0; j < 4; j++) o[j] = f2bf_hw(s[qn][zfg][j]);
                int g = zf2 * 2 + (lk >> 1);
                *(u16x4*)(rowp + ((g ^ (q & 7)) << 4) + (lk & 1) * 8) = o;
              }
            }

            asm volatile("s_waitcnt lgkmcnt(0)" ::: "memory");
            __builtin_amdgcn_sched_barrier(0);

            bf16x8 pf[2][2];
#pragma unroll
            for (int qn = 0; qn < 2; qn++)
#pragma unroll
              for (int kf = 0; kf < 2; kf++)
                pf[qn][kf] = *(const bf16x8*)(pw + (qn * 16 + lrow) * 128 + (((kf * 4 + lk) ^ (lrow & 7)) << 4));

#pragma unroll
            for (int qn = 0; qn < 2; qn++)
#pragma unroll
              for (int kf = 0; kf < 2; kf++)
                lsum[qn] = mfma16(pf[qn][kf], ones, lsum[qn]);

#pragma unroll
            for (int ef = 0; ef < 4; ef++) {
              int er = ef * 16 + lrow;
#pragma unroll
              for (int kf = 0; kf < 2; kf++) {
                int g = hf * 8 + kf * 4 + lk;
                bf16x8 vf = *(const bf16x8*)(vbase + er * 256 + ((g ^ (er & 15)) << 4));
                yacc[0][ef] = mfma16(pf[0][kf], vf, yacc[0][ef]);
                yacc[1][ef] = mfma16(pf[1][kf], vf, yacc[1][ef]);
              }
            }
          }
        }
      }

      __syncthreads();
    }

    // epilogue (native bf16 casts): q = qw + qn*16 + lk*4 + j, e = ef*16 + lrow
#pragma unroll
    for (int qn = 0; qn < 2; qn++) {
      f32x4 rinv;
#pragma unroll
      for (int j = 0; j < 4; j++) rinv[j] = 1.0f / lsum[qn][j];
#pragma unroll
      for (int ef = 0; ef < 4; ef++) {
        int col = h * 64 + ef * 16 + lrow;
#pragma unroll
        for (int j = 0; j < 4; j++) {
          int x = qw + qn * 16 + lk * 4 + j;
          Y[(b * 1024 + x) * 1024 + col] = f2bf_hw(yacc[qn][ef][j] * rinv[j]);
        }
      }
    }
  }
}

// ---------------- launch ----------------
extern "C" void kernel_launch(void* const* d_in, const int* in_sizes, int n_in,
                              void* d_out, int out_size, void* d_ws, size_t ws_size,
                              hipStream_t stream) {
  const float* x  = (const float*)d_in[0];
  const float* z  = (const float*)d_in[1];
  const float* Wq = (const float*)d_in[2];
  const float* bq = (const float*)d_in[3];
  const float* Wk = (const float*)d_in[4];
  const float* bk = (const float*)d_in[5];
  const float* Wv = (const float*)d_in[6];
  const float* bv = (const float*)d_in[7];
  const float* Wp = (const float*)d_in[8];
  const float* bp = (const float*)d_in[9];
  (void)in_sizes; (void)n_in; (void)out_size; (void)ws_size;

  char* ws = (char*)d_ws;
  unsigned short* Xb  = (unsigned short*)(ws + 0);
  unsigned short* Zb  = (unsigned short*)(ws + 16777216);
  unsigned short* Wqt = (unsigned short*)(ws + 33554432);  // Wqt/Wkt/Wvt contiguous = Wqkv
  unsigned short* Wkt = (unsigned short*)(ws + 35651584);
  unsigned short* Wvt = (unsigned short*)(ws + 37748736);
  unsigned short* Wpt = (unsigned short*)(ws + 39845888);
  unsigned short* Qp  = (unsigned short*)(ws + 41943040);
  unsigned short* Kp  = (unsigned short*)(ws + 58720256);
  unsigned short* Vtp = (unsigned short*)(ws + 75497472);

  k_prep<<<dim3(3072), dim3(256), 0, stream>>>(x, z, Xb, Wq, Wk, Wv, Wp, Wqt, Wkt, Wvt, Wpt);

  k_gemm_qkv<<<dim3(32, 24), dim3(256), 0, stream>>>(Xb, Zb, Wqt, bq, bk, bv, Qp, Kp, Vtp);

  k_attn<<<dim3(128, 4), dim3(256), 0, stream>>>(Qp, Kp, Vtp, Xb /*Y*/);

  k_gemm<<<dim3(32, 8), dim3(256), 0, stream>>>(Xb, Wpt, bp, d_out, 3, 1.0f);
}